// Round 1
// baseline (1025.621 us; speedup 1.0000x reference)
//
#include <hip/hip_runtime.h>

// ---------------------------------------------------------------------------
// Pipeline:
//  1. agnn_kernel (1 block): 2x AGNN on 32-node line graph -> hW = h @ W_e [32,64]
//  2. hist_kernel: deg[n] (in-degree) and cnt[n][t] (etype histogram) via atomics
//  3. scan_kernel (1 block): off = exscan(deg), pos = copy
//  4. sumew_kernel: sum_ew[n][d] = sum_t cnt[n][t] * hW[t][d]
//  5. scatter_kernel: CSR-by-dst src index list
//  6. spmm_kernel: aggF[n] = sum over incoming edges of feat[src]
//  7. gconv_kernel: out = tanh(feat@W1 + (aggF - sum_ew)@W2), final layer fuses pred head
// ---------------------------------------------------------------------------

__global__ __launch_bounds__(512) void agnn_kernel(
    const float* __restrict__ cl_h, const float* __restrict__ cl_w,
    const int* __restrict__ cl_src, const int* __restrict__ cl_dst,
    const float* __restrict__ W_e,
    const float* __restrict__ pb1, const float* __restrict__ pe1,
    const float* __restrict__ pb2, const float* __restrict__ pe2,
    float* __restrict__ hW, int ECL)
{
    __shared__ float h[32][16];
    __shared__ float nh[32][16];
    __shared__ float p[1024];
    __shared__ float m[32], ssum[32], nrm[32];
    const int tid = threadIdx.x;

    h[tid >> 4][tid & 15] = cl_h[tid];
    __syncthreads();

    for (int layer = 0; layer < 2; ++layer) {
        const float beta = layer ? *pb2 : *pb1;
        const float eps  = layer ? *pe2 : *pe1;

        // segment max over src
        if (tid < 32) {
            float mm = -1e30f;
            for (int e = 0; e < ECL; ++e)
                if (cl_src[e] == tid) mm = fmaxf(mm, beta * cl_w[e]);
            m[tid] = mm;
        }
        __syncthreads();
        for (int e = tid; e < ECL; e += 512)
            p[e] = __expf(beta * cl_w[e] - m[cl_src[e]]);
        __syncthreads();
        if (tid < 32) {
            float s = 0.f;
            for (int e = 0; e < ECL; ++e)
                if (cl_src[e] == tid) s += p[e];
            ssum[tid] = s;
        }
        __syncthreads();
        for (int e = tid; e < ECL; e += 512)
            p[e] = p[e] / ssum[cl_src[e]];
        // row l2 norms of h
        if (tid < 32) {
            float s = 0.f;
            for (int f = 0; f < 16; ++f) { float v = h[tid][f]; s += v * v; }
            nrm[tid] = fmaxf(sqrtf(s), 1e-12f);
        }
        __syncthreads();
        nh[tid >> 4][tid & 15] = h[tid >> 4][tid & 15] / nrm[tid >> 4];
        __syncthreads();
        {
            const int t = tid >> 4, f = tid & 15;
            float a = 0.f;
            for (int e = 0; e < ECL; ++e)
                if (cl_dst[e] == t) a += nh[cl_src[e]][f] * p[e];
            float v = (1.f + eps) * h[t][f] + a;
            h[t][f] = fmaxf(v, 0.f);   // only this thread touches h[t][f]
        }
        __syncthreads();
    }

    // hW[t][d] = sum_f h[t][f] * W_e[f][d]
    for (int o = tid; o < 2048; o += 512) {
        const int t = o >> 6, d = o & 63;
        float s = 0.f;
        #pragma unroll
        for (int f = 0; f < 16; ++f) s += h[t][f] * W_e[f * 64 + d];
        hW[o] = s;
    }
}

__global__ __launch_bounds__(256) void hist_kernel(
    const int* __restrict__ dst, const int* __restrict__ et,
    int* __restrict__ deg, int* __restrict__ cnt, int E)
{
    for (int i = blockIdx.x * 256 + threadIdx.x; i < E; i += gridDim.x * 256) {
        const int d = dst[i];
        atomicAdd(&deg[d], 1);
        atomicAdd(&cnt[d * 32 + et[i]], 1);
    }
}

__global__ __launch_bounds__(1024) void scan_kernel(
    const int* __restrict__ deg, int* __restrict__ off, int* __restrict__ pos, int N)
{
    __shared__ int buf[1024];
    __shared__ int carry;
    if (threadIdx.x == 0) carry = 0;
    __syncthreads();
    for (int base = 0; base < N; base += 1024) {
        const int i = base + threadIdx.x;
        const int v = (i < N) ? deg[i] : 0;
        buf[threadIdx.x] = v;
        __syncthreads();
        for (int s = 1; s < 1024; s <<= 1) {
            int t = (threadIdx.x >= s) ? buf[threadIdx.x - s] : 0;
            __syncthreads();
            buf[threadIdx.x] += t;
            __syncthreads();
        }
        const int excl = buf[threadIdx.x] - v;
        if (i < N) { off[i] = carry + excl; pos[i] = carry + excl; }
        __syncthreads();
        if (threadIdx.x == 0) carry += buf[1023];
        __syncthreads();
    }
    if (threadIdx.x == 0) off[N] = carry;
}

__global__ __launch_bounds__(256) void sumew_kernel(
    const int* __restrict__ cnt, const float* __restrict__ hW,
    float* __restrict__ sum_ew, int N)
{
    __shared__ float hWl[2048];
    for (int i = threadIdx.x; i < 2048; i += 256) hWl[i] = hW[i];
    __syncthreads();
    const int total = N * 64;
    for (int idx = blockIdx.x * 256 + threadIdx.x; idx < total; idx += gridDim.x * 256) {
        const int n = idx >> 6, d = idx & 63;
        float s = 0.f;
        #pragma unroll
        for (int t = 0; t < 32; ++t)
            s += (float)cnt[n * 32 + t] * hWl[t * 64 + d];
        sum_ew[idx] = s;
    }
}

__global__ __launch_bounds__(256) void scatter_kernel(
    const int* __restrict__ src, const int* __restrict__ dst,
    int* __restrict__ pos, int* __restrict__ ssrc, int E)
{
    for (int i = blockIdx.x * 256 + threadIdx.x; i < E; i += gridDim.x * 256) {
        const int p = atomicAdd(&pos[dst[i]], 1);
        ssrc[p] = src[i];
    }
}

// one wave per destination node; lane = feature dim
__global__ __launch_bounds__(256) void spmm_kernel(
    const float* __restrict__ feat, const int* __restrict__ off,
    const int* __restrict__ ssrc, float* __restrict__ agg, int N)
{
    const int lane = threadIdx.x & 63;
    const int n = blockIdx.x * 4 + (threadIdx.x >> 6);
    if (n >= N) return;
    const int beg = off[n], end = off[n + 1];
    float acc = 0.f;
    int i = beg;
    for (; i + 8 <= end; i += 8) {
        int s[8];
        #pragma unroll
        for (int j = 0; j < 8; ++j) s[j] = ssrc[i + j];
        #pragma unroll
        for (int j = 0; j < 8; ++j) acc += feat[(size_t)s[j] * 64 + lane];
    }
    for (; i < end; ++i) acc += feat[(size_t)ssrc[i] * 64 + lane];
    agg[(size_t)n * 64 + lane] = acc;
}

// one node per lane; W rows are wave-uniform (scalar loads); fa transposed via LDS
__global__ __launch_bounds__(64) void gconv_kernel(
    const float* __restrict__ feat, const float* __restrict__ aggF,
    const float* __restrict__ sumew,
    const float* __restrict__ W1, const float* __restrict__ W2,
    float* __restrict__ outp, int N, int final_mode,
    const float* __restrict__ Wp, const float* __restrict__ bp)
{
    __shared__ float fa[64][33];   // stride 33 -> conflict-free column reads
    const int lane = threadIdx.x;
    const int n0 = blockIdx.x * 64;
    const int n = n0 + lane;
    const bool valid = n < N;

    float acc[64];
    #pragma unroll
    for (int d = 0; d < 64; ++d) acc[d] = 0.f;

    for (int half = 0; half < 2; ++half) {
        const float* __restrict__ W = half ? W2 : W1;
        for (int kc = 0; kc < 2; ++kc) {
            __syncthreads();
            // stage 64 rows x 32 cols of (feat | aggF - sum_ew)
            #pragma unroll
            for (int it = 0; it < 8; ++it) {
                const int idx = it * 64 + lane;
                const int row = idx >> 3;      // 0..63
                const int c4  = idx & 7;       // 0..7
                const int rn = n0 + row;
                float4 v = make_float4(0.f, 0.f, 0.f, 0.f);
                if (rn < N) {
                    const size_t base = (size_t)rn * 64 + kc * 32 + c4 * 4;
                    if (half == 0) {
                        v = *reinterpret_cast<const float4*>(&feat[base]);
                    } else {
                        float4 a = *reinterpret_cast<const float4*>(&aggF[base]);
                        float4 s = *reinterpret_cast<const float4*>(&sumew[base]);
                        v = make_float4(a.x - s.x, a.y - s.y, a.z - s.z, a.w - s.w);
                    }
                }
                fa[row][c4 * 4 + 0] = v.x;
                fa[row][c4 * 4 + 1] = v.y;
                fa[row][c4 * 4 + 2] = v.z;
                fa[row][c4 * 4 + 3] = v.w;
            }
            __syncthreads();
            for (int k8 = 0; k8 < 32; ++k8) {
                const float fval = fa[lane][k8];
                const float* wrow = &W[(size_t)(kc * 32 + k8) * 64];
                #pragma unroll
                for (int d4 = 0; d4 < 16; ++d4) {
                    float4 w = *reinterpret_cast<const float4*>(&wrow[d4 * 4]);
                    acc[d4 * 4 + 0] += fval * w.x;
                    acc[d4 * 4 + 1] += fval * w.y;
                    acc[d4 * 4 + 2] += fval * w.z;
                    acc[d4 * 4 + 3] += fval * w.w;
                }
            }
        }
    }

    // tanh(x) = 1 - 2/(e^{2x}+1)  (inf-safe)
    #pragma unroll
    for (int d = 0; d < 64; ++d) {
        const float e2 = __expf(2.f * acc[d]);
        acc[d] = 1.f - 2.f / (e2 + 1.f);
    }

    if (!final_mode) {
        if (valid) {
            #pragma unroll
            for (int d4 = 0; d4 < 16; ++d4) {
                float4 v = make_float4(acc[d4 * 4], acc[d4 * 4 + 1],
                                       acc[d4 * 4 + 2], acc[d4 * 4 + 3]);
                *reinterpret_cast<float4*>(&outp[(size_t)n * 64 + d4 * 4]) = v;
            }
        }
    } else {
        float o[16];
        #pragma unroll
        for (int c = 0; c < 16; ++c) o[c] = bp[c];
        #pragma unroll
        for (int d = 0; d < 64; ++d) {
            const float t = acc[d];
            #pragma unroll
            for (int c = 0; c < 16; ++c) o[c] += t * Wp[d * 16 + c];
        }
        if (valid) {
            #pragma unroll
            for (int c4 = 0; c4 < 4; ++c4) {
                float4 v = make_float4(o[c4 * 4], o[c4 * 4 + 1],
                                       o[c4 * 4 + 2], o[c4 * 4 + 3]);
                *reinterpret_cast<float4*>(&outp[(size_t)n * 16 + c4 * 4]) = v;
            }
        }
    }
}

extern "C" void kernel_launch(void* const* d_in, const int* in_sizes, int n_in,
                              void* d_out, int out_size, void* d_ws, size_t ws_size,
                              hipStream_t stream)
{
    const float* cl_h   = (const float*)d_in[0];
    const float* cl_w   = (const float*)d_in[1];
    const int*   cl_src = (const int*)d_in[2];
    const int*   cl_dst = (const int*)d_in[3];
    const int*   g_src  = (const int*)d_in[4];
    const int*   g_dst  = (const int*)d_in[5];
    const int*   g_et   = (const int*)d_in[6];
    const float* feats  = (const float*)d_in[7];
    const float* W_e    = (const float*)d_in[8];
    const float* b1     = (const float*)d_in[9];
    const float* e1     = (const float*)d_in[10];
    const float* b2     = (const float*)d_in[11];
    const float* e2     = (const float*)d_in[12];
    const float* W1a    = (const float*)d_in[13];
    const float* W2a    = (const float*)d_in[14];
    const float* W1b    = (const float*)d_in[15];
    const float* W2b    = (const float*)d_in[16];
    const float* Wp     = (const float*)d_in[17];
    const float* bp     = (const float*)d_in[18];
    const int ECL = in_sizes[1];
    const int E   = in_sizes[4];
    const int N   = in_sizes[7] / 64;

    char* w = (char*)d_ws;
    auto carve = [&](size_t bytes) {
        char* r = w;
        w += (bytes + 255) & ~(size_t)255;
        return r;
    };
    float* hW     = (float*)carve(32 * 64 * sizeof(float));
    float* sum_ew = (float*)carve((size_t)N * 64 * sizeof(float));
    int*   deg    = (int*)carve((size_t)N * sizeof(int));
    int*   off    = (int*)carve((size_t)(N + 1) * sizeof(int));
    int*   pos    = (int*)carve((size_t)N * sizeof(int));
    float* aggF   = (float*)carve((size_t)N * 64 * sizeof(float));
    float* x1     = (float*)carve((size_t)N * 64 * sizeof(float));
    size_t cntBytes = (size_t)N * 32 * sizeof(int);
    size_t srcBytes = (size_t)E * sizeof(int);
    int*   cnt    = (int*)carve(cntBytes > srcBytes ? cntBytes : srcBytes);
    int*   ssrc   = cnt;   // alias: scatter runs after sumew has consumed cnt

    hipMemsetAsync(cnt, 0, cntBytes, stream);
    hipMemsetAsync(deg, 0, (size_t)N * sizeof(int), stream);

    agnn_kernel<<<1, 512, 0, stream>>>(cl_h, cl_w, cl_src, cl_dst, W_e,
                                       b1, e1, b2, e2, hW, ECL);
    hist_kernel<<<2048, 256, 0, stream>>>(g_dst, g_et, deg, cnt, E);
    scan_kernel<<<1, 1024, 0, stream>>>(deg, off, pos, N);
    sumew_kernel<<<3200, 256, 0, stream>>>(cnt, hW, sum_ew, N);
    scatter_kernel<<<2048, 256, 0, stream>>>(g_src, g_dst, pos, ssrc, E);
    spmm_kernel<<<(N + 3) / 4, 256, 0, stream>>>(feats, off, ssrc, aggF, N);
    gconv_kernel<<<(N + 63) / 64, 64, 0, stream>>>(feats, aggF, sum_ew,
                                                   W1a, W2a, x1, N, 0, Wp, bp);
    spmm_kernel<<<(N + 3) / 4, 256, 0, stream>>>(x1, off, ssrc, aggF, N);
    gconv_kernel<<<(N + 63) / 64, 64, 0, stream>>>(x1, aggF, sum_ew,
                                                   W1b, W2b, (float*)d_out, N, 1, Wp, bp);
}

// Round 2
// 622.388 us; speedup vs baseline: 1.6479x; 1.6479x over previous
//
#include <hip/hip_runtime.h>

// ---------------------------------------------------------------------------
// Pipeline:
//  1. agnn_kernel (1 block): 2x AGNN on 32-node line graph -> hW = h @ W_e [32,64]
//     (edge arrays staged in LDS; segment reductions parallelized 16-thread/segment)
//  2. hist_kernel: cnt[n][t] etype histogram via atomics
//  3. sumew_kernel: sum_ew[n][d] = sum_t cnt[n][t]*hW[t][d]; also emits deg[n]
//  4. scan_kernel (1 block, wave shuffle): off = exscan(deg), pos = copy
//  5. scatter_kernel: CSR-by-dst src index list
//  6. spmm_kernel: aggF[n] = sum over incoming edges of feat[src]
//  7. gconv_kernel: out = tanh(feat@W1 + (aggF - sum_ew)@W2), final layer fuses pred head
// ---------------------------------------------------------------------------

__global__ __launch_bounds__(512) void agnn_kernel(
    const float* __restrict__ cl_h, const float* __restrict__ cl_w,
    const int* __restrict__ cl_src, const int* __restrict__ cl_dst,
    const float* __restrict__ W_e,
    const float* __restrict__ pb1, const float* __restrict__ pe1,
    const float* __restrict__ pb2, const float* __restrict__ pe2,
    float* __restrict__ hW, int ECL)
{
    __shared__ float w_s[1024];
    __shared__ int   src_s[1024];
    __shared__ int   dst_s[1024];
    __shared__ float h[32][16];
    __shared__ float nh[32][16];
    __shared__ float p[1024];
    __shared__ float red[32][16];
    __shared__ float m[32], ssum[32], nrm[32];
    const int tid = threadIdx.x;
    const int seg = tid >> 4, j = tid & 15;   // 16 threads per segment

    for (int e = tid; e < ECL; e += 512) {
        w_s[e] = cl_w[e]; src_s[e] = cl_src[e]; dst_s[e] = cl_dst[e];
    }
    h[tid >> 4][tid & 15] = cl_h[tid];        // 32*16 == 512
    __syncthreads();

    for (int layer = 0; layer < 2; ++layer) {
        const float beta = layer ? *pb2 : *pb1;
        const float eps  = layer ? *pe2 : *pe1;

        // ---- segment max over src (parallel LDS scan, deterministic) ----
        {
            float mm = -3.4e38f;
            for (int e = j; e < ECL; e += 16)
                if (src_s[e] == seg) mm = fmaxf(mm, beta * w_s[e]);
            red[seg][j] = mm;
        }
        __syncthreads();
        if (tid < 32) {
            float mm = red[tid][0];
            #pragma unroll
            for (int k = 1; k < 16; ++k) mm = fmaxf(mm, red[tid][k]);
            m[tid] = mm;
        }
        __syncthreads();
        for (int e = tid; e < ECL; e += 512)
            p[e] = __expf(beta * w_s[e] - m[src_s[e]]);
        __syncthreads();
        // ---- segment sum (parallel, fixed combine order -> deterministic) ----
        {
            float s = 0.f;
            for (int e = j; e < ECL; e += 16)
                if (src_s[e] == seg) s += p[e];
            red[seg][j] = s;
        }
        __syncthreads();
        if (tid < 32) {
            float s = 0.f;
            #pragma unroll
            for (int k = 0; k < 16; ++k) s += red[tid][k];
            ssum[tid] = s;
            float q = 0.f;
            #pragma unroll
            for (int f = 0; f < 16; ++f) { float v = h[tid][f]; q += v * v; }
            nrm[tid] = fmaxf(sqrtf(q), 1e-12f);
        }
        __syncthreads();
        for (int e = tid; e < ECL; e += 512)
            p[e] = p[e] / ssum[src_s[e]];
        nh[tid >> 4][tid & 15] = h[tid >> 4][tid & 15] / nrm[tid >> 4];
        __syncthreads();
        // ---- aggregate: each thread owns one (t,f) output, scans edges in LDS ----
        {
            const int t = tid >> 4, f = tid & 15;
            float a = 0.f;
            for (int e = 0; e < ECL; ++e)
                if (dst_s[e] == t) a += nh[src_s[e]][f] * p[e];
            float v = (1.f + eps) * h[t][f] + a;
            h[t][f] = fmaxf(v, 0.f);   // only this thread touches h[t][f]
        }
        __syncthreads();
    }

    // hW[t][d] = sum_f h[t][f] * W_e[f][d]
    for (int o = tid; o < 2048; o += 512) {
        const int t = o >> 6, d = o & 63;
        float s = 0.f;
        #pragma unroll
        for (int f = 0; f < 16; ++f) s += h[t][f] * W_e[f * 64 + d];
        hW[o] = s;
    }
}

__global__ __launch_bounds__(256) void hist_kernel(
    const int* __restrict__ dst, const int* __restrict__ et,
    int* __restrict__ cnt, int E)
{
    for (int i = blockIdx.x * 256 + threadIdx.x; i < E; i += gridDim.x * 256) {
        atomicAdd(&cnt[dst[i] * 32 + et[i]], 1);
    }
}

// sum_ew[n][d] = sum_t cnt[n][t]*hW[t][d]; lane d==0 also writes deg[n]
__global__ __launch_bounds__(256) void sumew_kernel(
    const int* __restrict__ cnt, const float* __restrict__ hW,
    float* __restrict__ sum_ew, int* __restrict__ deg, int N)
{
    __shared__ float hWl[2048];
    for (int i = threadIdx.x; i < 2048; i += 256) hWl[i] = hW[i];
    __syncthreads();
    const int total = N * 64;
    for (int idx = blockIdx.x * 256 + threadIdx.x; idx < total; idx += gridDim.x * 256) {
        const int n = idx >> 6, d = idx & 63;
        float s = 0.f;
        int dg = 0;
        #pragma unroll
        for (int t = 0; t < 32; ++t) {
            const int c = cnt[n * 32 + t];      // wave-uniform per n -> broadcast
            s += (float)c * hWl[t * 64 + d];
            dg += c;
        }
        sum_ew[idx] = s;
        if (d == 0) deg[n] = dg;
    }
}

// single block, wave-shuffle exclusive scan of deg -> off, pos
__global__ __launch_bounds__(1024) void scan_kernel(
    const int* __restrict__ deg, int* __restrict__ off, int* __restrict__ pos, int N)
{
    __shared__ int wsum[16];
    const int tid = threadIdx.x;
    const int lane = tid & 63, wv = tid >> 6;
    int carry = 0;
    for (int base = 0; base < N; base += 1024) {
        const int i = base + tid;
        const int v = (i < N) ? deg[i] : 0;
        int x = v;
        #pragma unroll
        for (int s = 1; s < 64; s <<= 1) {
            const int t = __shfl_up(x, s, 64);
            if (lane >= s) x += t;
        }
        if (lane == 63) wsum[wv] = x;
        __syncthreads();
        if (wv == 0 && lane < 16) {
            int y = wsum[lane];
            #pragma unroll
            for (int s = 1; s < 16; s <<= 1) {
                const int t = __shfl_up(y, s, 64);
                if (lane >= s) y += t;
            }
            wsum[lane] = y;   // inclusive scan of wave sums
        }
        __syncthreads();
        const int wave_off = (wv == 0) ? 0 : wsum[wv - 1];
        const int excl = carry + wave_off + x - v;
        if (i < N) { off[i] = excl; pos[i] = excl; }
        carry += wsum[15];
        __syncthreads();
    }
    if (tid == 0) off[N] = carry;
}

__global__ __launch_bounds__(256) void scatter_kernel(
    const int* __restrict__ src, const int* __restrict__ dst,
    int* __restrict__ pos, int* __restrict__ ssrc, int E)
{
    for (int i = blockIdx.x * 256 + threadIdx.x; i < E; i += gridDim.x * 256) {
        const int p = atomicAdd(&pos[dst[i]], 1);
        ssrc[p] = src[i];
    }
}

// one wave per destination node; lane = feature dim
__global__ __launch_bounds__(256) void spmm_kernel(
    const float* __restrict__ feat, const int* __restrict__ off,
    const int* __restrict__ ssrc, float* __restrict__ agg, int N)
{
    const int lane = threadIdx.x & 63;
    const int n = blockIdx.x * 4 + (threadIdx.x >> 6);
    if (n >= N) return;
    const int beg = off[n], end = off[n + 1];
    float acc = 0.f;
    int i = beg;
    for (; i + 8 <= end; i += 8) {
        int s[8];
        #pragma unroll
        for (int j = 0; j < 8; ++j) s[j] = ssrc[i + j];
        #pragma unroll
        for (int j = 0; j < 8; ++j) acc += feat[(size_t)s[j] * 64 + lane];
    }
    for (; i < end; ++i) acc += feat[(size_t)ssrc[i] * 64 + lane];
    agg[(size_t)n * 64 + lane] = acc;
}

// one node per lane; W rows are wave-uniform (scalar loads); fa transposed via LDS
__global__ __launch_bounds__(64) void gconv_kernel(
    const float* __restrict__ feat, const float* __restrict__ aggF,
    const float* __restrict__ sumew,
    const float* __restrict__ W1, const float* __restrict__ W2,
    float* __restrict__ outp, int N, int final_mode,
    const float* __restrict__ Wp, const float* __restrict__ bp)
{
    __shared__ float fa[64][33];   // stride 33 -> conflict-free column reads
    const int lane = threadIdx.x;
    const int n0 = blockIdx.x * 64;
    const int n = n0 + lane;
    const bool valid = n < N;

    float acc[64];
    #pragma unroll
    for (int d = 0; d < 64; ++d) acc[d] = 0.f;

    for (int half = 0; half < 2; ++half) {
        const float* __restrict__ W = half ? W2 : W1;
        for (int kc = 0; kc < 2; ++kc) {
            __syncthreads();
            #pragma unroll
            for (int it = 0; it < 8; ++it) {
                const int idx = it * 64 + lane;
                const int row = idx >> 3;      // 0..63
                const int c4  = idx & 7;       // 0..7
                const int rn = n0 + row;
                float4 v = make_float4(0.f, 0.f, 0.f, 0.f);
                if (rn < N) {
                    const size_t base = (size_t)rn * 64 + kc * 32 + c4 * 4;
                    if (half == 0) {
                        v = *reinterpret_cast<const float4*>(&feat[base]);
                    } else {
                        float4 a = *reinterpret_cast<const float4*>(&aggF[base]);
                        float4 s = *reinterpret_cast<const float4*>(&sumew[base]);
                        v = make_float4(a.x - s.x, a.y - s.y, a.z - s.z, a.w - s.w);
                    }
                }
                fa[row][c4 * 4 + 0] = v.x;
                fa[row][c4 * 4 + 1] = v.y;
                fa[row][c4 * 4 + 2] = v.z;
                fa[row][c4 * 4 + 3] = v.w;
            }
            __syncthreads();
            for (int k8 = 0; k8 < 32; ++k8) {
                const float fval = fa[lane][k8];
                const float* wrow = &W[(size_t)(kc * 32 + k8) * 64];
                #pragma unroll
                for (int d4 = 0; d4 < 16; ++d4) {
                    float4 w = *reinterpret_cast<const float4*>(&wrow[d4 * 4]);
                    acc[d4 * 4 + 0] += fval * w.x;
                    acc[d4 * 4 + 1] += fval * w.y;
                    acc[d4 * 4 + 2] += fval * w.z;
                    acc[d4 * 4 + 3] += fval * w.w;
                }
            }
        }
    }

    // tanh(x) = 1 - 2/(e^{2x}+1)  (inf-safe)
    #pragma unroll
    for (int d = 0; d < 64; ++d) {
        const float e2 = __expf(2.f * acc[d]);
        acc[d] = 1.f - 2.f / (e2 + 1.f);
    }

    if (!final_mode) {
        if (valid) {
            #pragma unroll
            for (int d4 = 0; d4 < 16; ++d4) {
                float4 v = make_float4(acc[d4 * 4], acc[d4 * 4 + 1],
                                       acc[d4 * 4 + 2], acc[d4 * 4 + 3]);
                *reinterpret_cast<float4*>(&outp[(size_t)n * 64 + d4 * 4]) = v;
            }
        }
    } else {
        float o[16];
        #pragma unroll
        for (int c = 0; c < 16; ++c) o[c] = bp[c];
        #pragma unroll
        for (int d = 0; d < 64; ++d) {
            const float t = acc[d];
            #pragma unroll
            for (int c = 0; c < 16; ++c) o[c] += t * Wp[d * 16 + c];
        }
        if (valid) {
            #pragma unroll
            for (int c4 = 0; c4 < 4; ++c4) {
                float4 v = make_float4(o[c4 * 4], o[c4 * 4 + 1],
                                       o[c4 * 4 + 2], o[c4 * 4 + 3]);
                *reinterpret_cast<float4*>(&outp[(size_t)n * 16 + c4 * 4]) = v;
            }
        }
    }
}

extern "C" void kernel_launch(void* const* d_in, const int* in_sizes, int n_in,
                              void* d_out, int out_size, void* d_ws, size_t ws_size,
                              hipStream_t stream)
{
    const float* cl_h   = (const float*)d_in[0];
    const float* cl_w   = (const float*)d_in[1];
    const int*   cl_src = (const int*)d_in[2];
    const int*   cl_dst = (const int*)d_in[3];
    const int*   g_src  = (const int*)d_in[4];
    const int*   g_dst  = (const int*)d_in[5];
    const int*   g_et   = (const int*)d_in[6];
    const float* feats  = (const float*)d_in[7];
    const float* W_e    = (const float*)d_in[8];
    const float* b1     = (const float*)d_in[9];
    const float* e1     = (const float*)d_in[10];
    const float* b2     = (const float*)d_in[11];
    const float* e2     = (const float*)d_in[12];
    const float* W1a    = (const float*)d_in[13];
    const float* W2a    = (const float*)d_in[14];
    const float* W1b    = (const float*)d_in[15];
    const float* W2b    = (const float*)d_in[16];
    const float* Wp     = (const float*)d_in[17];
    const float* bp     = (const float*)d_in[18];
    const int ECL = in_sizes[1];
    const int E   = in_sizes[4];
    const int N   = in_sizes[7] / 64;

    char* w = (char*)d_ws;
    auto carve = [&](size_t bytes) {
        char* r = w;
        w += (bytes + 255) & ~(size_t)255;
        return r;
    };
    float* hW     = (float*)carve(32 * 64 * sizeof(float));
    float* sum_ew = (float*)carve((size_t)N * 64 * sizeof(float));
    int*   deg    = (int*)carve((size_t)N * sizeof(int));
    int*   off    = (int*)carve((size_t)(N + 1) * sizeof(int));
    int*   pos    = (int*)carve((size_t)N * sizeof(int));
    float* aggF   = (float*)carve((size_t)N * 64 * sizeof(float));
    float* x1     = (float*)carve((size_t)N * 64 * sizeof(float));
    size_t cntBytes = (size_t)N * 32 * sizeof(int);
    size_t srcBytes = (size_t)E * sizeof(int);
    int*   cnt    = (int*)carve(cntBytes > srcBytes ? cntBytes : srcBytes);
    int*   ssrc   = cnt;   // alias: scatter runs after sumew has consumed cnt

    hipMemsetAsync(cnt, 0, cntBytes, stream);

    agnn_kernel<<<1, 512, 0, stream>>>(cl_h, cl_w, cl_src, cl_dst, W_e,
                                       b1, e1, b2, e2, hW, ECL);
    hist_kernel<<<2048, 256, 0, stream>>>(g_dst, g_et, cnt, E);
    sumew_kernel<<<3200, 256, 0, stream>>>(cnt, hW, sum_ew, deg, N);
    scan_kernel<<<1, 1024, 0, stream>>>(deg, off, pos, N);
    scatter_kernel<<<2048, 256, 0, stream>>>(g_src, g_dst, pos, ssrc, E);
    spmm_kernel<<<(N + 3) / 4, 256, 0, stream>>>(feats, off, ssrc, aggF, N);
    gconv_kernel<<<(N + 63) / 64, 64, 0, stream>>>(feats, aggF, sum_ew,
                                                   W1a, W2a, x1, N, 0, Wp, bp);
    spmm_kernel<<<(N + 3) / 4, 256, 0, stream>>>(x1, off, ssrc, aggF, N);
    gconv_kernel<<<(N + 63) / 64, 64, 0, stream>>>(x1, aggF, sum_ew,
                                                   W1b, W2b, (float*)d_out, N, 1, Wp, bp);
}

// Round 3
// 505.067 us; speedup vs baseline: 2.0307x; 1.2323x over previous
//
#include <hip/hip_runtime.h>

// ---------------------------------------------------------------------------
// Pipeline:
//  1. agnn_kernel (1 block): 2x AGNN on 32-node line graph -> hW = h @ W_e [32,64]
//     (edges in LDS; seg-max via LDS atomicMax on ordered-uint; aggregate 16-way/segment)
//  2. hist_kernel: cnt[n][t] etype histogram via atomics
//  3. sumew_kernel: sum_ew[n][d] = sum_t cnt[n][t]*hW[t][d]; also emits deg[n]
//  4. scan_kernel (1 block, wave shuffle): off = exscan(deg), pos = copy
//  5. scatter_kernel: CSR-by-dst src index list
//  6. spmm_kernel: aggF[n] = sum over incoming edges of feat[src]
//  7. gconv_kernel: out = tanh(feat@W1 + (aggF - sum_ew)@W2), final layer fuses pred head
// ---------------------------------------------------------------------------

__device__ __forceinline__ unsigned ford_enc(float v) {
    unsigned b = __float_as_uint(v);
    return (b & 0x80000000u) ? ~b : (b | 0x80000000u);
}
__device__ __forceinline__ float ford_dec(unsigned k) {
    return __uint_as_float((k & 0x80000000u) ? (k ^ 0x80000000u) : ~k);
}

__global__ __launch_bounds__(512) void agnn_kernel(
    const float* __restrict__ cl_h, const float* __restrict__ cl_w,
    const int* __restrict__ cl_src, const int* __restrict__ cl_dst,
    const float* __restrict__ W_e,
    const float* __restrict__ pb1, const float* __restrict__ pe1,
    const float* __restrict__ pb2, const float* __restrict__ pe2,
    float* __restrict__ hW, int ECL)
{
    __shared__ float w_s[1024];
    __shared__ int   src_s[1024];
    __shared__ int   dst_s[1024];
    __shared__ float h[32][16];
    __shared__ float nh[32][16];
    __shared__ float p[1024];
    __shared__ float red[32][16];
    __shared__ float acc16[32][16][16];   // [t][j][f] aggregate partials, 32 KB
    __shared__ unsigned mI[32];
    __shared__ float m[32], ssum[32], nrm[32];
    const int tid = threadIdx.x;
    const int seg = tid >> 4, j = tid & 15;   // 16 threads per segment

    for (int e = tid; e < ECL; e += 512) {
        w_s[e] = cl_w[e]; src_s[e] = cl_src[e]; dst_s[e] = cl_dst[e];
    }
    h[tid >> 4][tid & 15] = cl_h[tid];        // 32*16 == 512
    __syncthreads();

    for (int layer = 0; layer < 2; ++layer) {
        const float beta = layer ? *pb2 : *pb1;
        const float eps  = layer ? *pe2 : *pe1;

        // ---- segment max over src: LDS atomicMax (order-independent => deterministic)
        if (tid < 32) mI[tid] = ford_enc(-3.4e38f);
        __syncthreads();
        for (int e = tid; e < ECL; e += 512)
            atomicMax(&mI[src_s[e]], ford_enc(beta * w_s[e]));
        __syncthreads();
        if (tid < 32) m[tid] = ford_dec(mI[tid]);
        __syncthreads();

        for (int e = tid; e < ECL; e += 512)
            p[e] = __expf(beta * w_s[e] - m[src_s[e]]);
        __syncthreads();

        // ---- segment sum: 16 fixed-order partials per segment (deterministic) ----
        {
            float s = 0.f;
            #pragma unroll 4
            for (int e = j; e < ECL; e += 16)
                s += (src_s[e] == seg) ? p[e] : 0.f;
            red[seg][j] = s;
        }
        __syncthreads();
        if (tid < 32) {
            float s = 0.f;
            #pragma unroll
            for (int k = 0; k < 16; ++k) s += red[tid][k];
            ssum[tid] = s;
            float q = 0.f;
            #pragma unroll
            for (int f = 0; f < 16; ++f) { float v = h[tid][f]; q += v * v; }
            nrm[tid] = fmaxf(sqrtf(q), 1e-12f);
        }
        __syncthreads();
        for (int e = tid; e < ECL; e += 512)
            p[e] = p[e] / ssum[src_s[e]];
        nh[tid >> 4][tid & 15] = h[tid >> 4][tid & 15] / nrm[tid >> 4];
        __syncthreads();

        // ---- aggregate: thread (t,j) scans e==j (mod 16), owns 16-float row ----
        {
            float facc[16];
            #pragma unroll
            for (int f = 0; f < 16; ++f) facc[f] = 0.f;
            #pragma unroll 4
            for (int e = j; e < ECL; e += 16) {
                if (dst_s[e] == seg) {
                    const float pe = p[e];
                    const float4* nhrow = reinterpret_cast<const float4*>(&nh[src_s[e]][0]);
                    const float4 a0 = nhrow[0], a1 = nhrow[1], a2 = nhrow[2], a3 = nhrow[3];
                    facc[0] += pe * a0.x; facc[1] += pe * a0.y; facc[2] += pe * a0.z; facc[3] += pe * a0.w;
                    facc[4] += pe * a1.x; facc[5] += pe * a1.y; facc[6] += pe * a1.z; facc[7] += pe * a1.w;
                    facc[8] += pe * a2.x; facc[9] += pe * a2.y; facc[10] += pe * a2.z; facc[11] += pe * a2.w;
                    facc[12] += pe * a3.x; facc[13] += pe * a3.y; facc[14] += pe * a3.z; facc[15] += pe * a3.w;
                }
            }
            #pragma unroll
            for (int f = 0; f < 16; ++f) acc16[seg][j][f] = facc[f];
        }
        __syncthreads();
        {
            const int t = tid >> 4, f = tid & 15;
            float a = 0.f;
            #pragma unroll
            for (int k = 0; k < 16; ++k) a += acc16[t][k][f];
            float v = (1.f + eps) * h[t][f] + a;
            h[t][f] = fmaxf(v, 0.f);   // only this thread touches h[t][f]
        }
        __syncthreads();
    }

    // hW[t][d] = sum_f h[t][f] * W_e[f][d]
    for (int o = tid; o < 2048; o += 512) {
        const int t = o >> 6, d = o & 63;
        float s = 0.f;
        #pragma unroll
        for (int f = 0; f < 16; ++f) s += h[t][f] * W_e[f * 64 + d];
        hW[o] = s;
    }
}

__global__ __launch_bounds__(256) void hist_kernel(
    const int* __restrict__ dst, const int* __restrict__ et,
    int* __restrict__ cnt, int E)
{
    for (int i = blockIdx.x * 256 + threadIdx.x; i < E; i += gridDim.x * 256) {
        atomicAdd(&cnt[dst[i] * 32 + et[i]], 1);
    }
}

// sum_ew[n][d] = sum_t cnt[n][t]*hW[t][d]; lane d==0 also writes deg[n]
__global__ __launch_bounds__(256) void sumew_kernel(
    const int* __restrict__ cnt, const float* __restrict__ hW,
    float* __restrict__ sum_ew, int* __restrict__ deg, int N)
{
    __shared__ float hWl[2048];
    for (int i = threadIdx.x; i < 2048; i += 256) hWl[i] = hW[i];
    __syncthreads();
    const int total = N * 64;
    for (int idx = blockIdx.x * 256 + threadIdx.x; idx < total; idx += gridDim.x * 256) {
        const int n = idx >> 6, d = idx & 63;
        float s = 0.f;
        int dg = 0;
        #pragma unroll
        for (int t = 0; t < 32; ++t) {
            const int c = cnt[n * 32 + t];      // wave-uniform per n -> broadcast
            s += (float)c * hWl[t * 64 + d];
            dg += c;
        }
        sum_ew[idx] = s;
        if (d == 0) deg[n] = dg;
    }
}

// single block, wave-shuffle exclusive scan of deg -> off, pos
__global__ __launch_bounds__(1024) void scan_kernel(
    const int* __restrict__ deg, int* __restrict__ off, int* __restrict__ pos, int N)
{
    __shared__ int wsum[16];
    const int tid = threadIdx.x;
    const int lane = tid & 63, wv = tid >> 6;
    int carry = 0;
    for (int base = 0; base < N; base += 1024) {
        const int i = base + tid;
        const int v = (i < N) ? deg[i] : 0;
        int x = v;
        #pragma unroll
        for (int s = 1; s < 64; s <<= 1) {
            const int t = __shfl_up(x, s, 64);
            if (lane >= s) x += t;
        }
        if (lane == 63) wsum[wv] = x;
        __syncthreads();
        if (wv == 0 && lane < 16) {
            int y = wsum[lane];
            #pragma unroll
            for (int s = 1; s < 16; s <<= 1) {
                const int t = __shfl_up(y, s, 64);
                if (lane >= s) y += t;
            }
            wsum[lane] = y;   // inclusive scan of wave sums
        }
        __syncthreads();
        const int wave_off = (wv == 0) ? 0 : wsum[wv - 1];
        const int excl = carry + wave_off + x - v;
        if (i < N) { off[i] = excl; pos[i] = excl; }
        carry += wsum[15];
        __syncthreads();
    }
    if (tid == 0) off[N] = carry;
}

__global__ __launch_bounds__(256) void scatter_kernel(
    const int* __restrict__ src, const int* __restrict__ dst,
    int* __restrict__ pos, int* __restrict__ ssrc, int E)
{
    for (int i = blockIdx.x * 256 + threadIdx.x; i < E; i += gridDim.x * 256) {
        const int p = atomicAdd(&pos[dst[i]], 1);
        ssrc[p] = src[i];
    }
}

// one wave per destination node; lane = feature dim
__global__ __launch_bounds__(256) void spmm_kernel(
    const float* __restrict__ feat, const int* __restrict__ off,
    const int* __restrict__ ssrc, float* __restrict__ agg, int N)
{
    const int lane = threadIdx.x & 63;
    const int n = blockIdx.x * 4 + (threadIdx.x >> 6);
    if (n >= N) return;
    const int beg = off[n], end = off[n + 1];
    float acc = 0.f;
    int i = beg;
    for (; i + 8 <= end; i += 8) {
        int s[8];
        #pragma unroll
        for (int j = 0; j < 8; ++j) s[j] = ssrc[i + j];
        #pragma unroll
        for (int j = 0; j < 8; ++j) acc += feat[(size_t)s[j] * 64 + lane];
    }
    for (; i < end; ++i) acc += feat[(size_t)ssrc[i] * 64 + lane];
    agg[(size_t)n * 64 + lane] = acc;
}

// one node per lane; W rows are wave-uniform (scalar loads); fa transposed via LDS
__global__ __launch_bounds__(64) void gconv_kernel(
    const float* __restrict__ feat, const float* __restrict__ aggF,
    const float* __restrict__ sumew,
    const float* __restrict__ W1, const float* __restrict__ W2,
    float* __restrict__ outp, int N, int final_mode,
    const float* __restrict__ Wp, const float* __restrict__ bp)
{
    __shared__ float fa[64][33];   // stride 33 -> conflict-free column reads
    const int lane = threadIdx.x;
    const int n0 = blockIdx.x * 64;
    const int n = n0 + lane;
    const bool valid = n < N;

    float acc[64];
    #pragma unroll
    for (int d = 0; d < 64; ++d) acc[d] = 0.f;

    for (int half = 0; half < 2; ++half) {
        const float* __restrict__ W = half ? W2 : W1;
        for (int kc = 0; kc < 2; ++kc) {
            __syncthreads();
            #pragma unroll
            for (int it = 0; it < 8; ++it) {
                const int idx = it * 64 + lane;
                const int row = idx >> 3;      // 0..63
                const int c4  = idx & 7;       // 0..7
                const int rn = n0 + row;
                float4 v = make_float4(0.f, 0.f, 0.f, 0.f);
                if (rn < N) {
                    const size_t base = (size_t)rn * 64 + kc * 32 + c4 * 4;
                    if (half == 0) {
                        v = *reinterpret_cast<const float4*>(&feat[base]);
                    } else {
                        float4 a = *reinterpret_cast<const float4*>(&aggF[base]);
                        float4 s = *reinterpret_cast<const float4*>(&sumew[base]);
                        v = make_float4(a.x - s.x, a.y - s.y, a.z - s.z, a.w - s.w);
                    }
                }
                fa[row][c4 * 4 + 0] = v.x;
                fa[row][c4 * 4 + 1] = v.y;
                fa[row][c4 * 4 + 2] = v.z;
                fa[row][c4 * 4 + 3] = v.w;
            }
            __syncthreads();
            for (int k8 = 0; k8 < 32; ++k8) {
                const float fval = fa[lane][k8];
                const float* wrow = &W[(size_t)(kc * 32 + k8) * 64];
                #pragma unroll
                for (int d4 = 0; d4 < 16; ++d4) {
                    float4 w = *reinterpret_cast<const float4*>(&wrow[d4 * 4]);
                    acc[d4 * 4 + 0] += fval * w.x;
                    acc[d4 * 4 + 1] += fval * w.y;
                    acc[d4 * 4 + 2] += fval * w.z;
                    acc[d4 * 4 + 3] += fval * w.w;
                }
            }
        }
    }

    // tanh(x) = 1 - 2/(e^{2x}+1)  (inf-safe)
    #pragma unroll
    for (int d = 0; d < 64; ++d) {
        const float e2 = __expf(2.f * acc[d]);
        acc[d] = 1.f - 2.f / (e2 + 1.f);
    }

    if (!final_mode) {
        if (valid) {
            #pragma unroll
            for (int d4 = 0; d4 < 16; ++d4) {
                float4 v = make_float4(acc[d4 * 4], acc[d4 * 4 + 1],
                                       acc[d4 * 4 + 2], acc[d4 * 4 + 3]);
                *reinterpret_cast<float4*>(&outp[(size_t)n * 64 + d4 * 4]) = v;
            }
        }
    } else {
        float o[16];
        #pragma unroll
        for (int c = 0; c < 16; ++c) o[c] = bp[c];
        #pragma unroll
        for (int d = 0; d < 64; ++d) {
            const float t = acc[d];
            #pragma unroll
            for (int c = 0; c < 16; ++c) o[c] += t * Wp[d * 16 + c];
        }
        if (valid) {
            #pragma unroll
            for (int c4 = 0; c4 < 4; ++c4) {
                float4 v = make_float4(o[c4 * 4], o[c4 * 4 + 1],
                                       o[c4 * 4 + 2], o[c4 * 4 + 3]);
                *reinterpret_cast<float4*>(&outp[(size_t)n * 16 + c4 * 4]) = v;
            }
        }
    }
}

extern "C" void kernel_launch(void* const* d_in, const int* in_sizes, int n_in,
                              void* d_out, int out_size, void* d_ws, size_t ws_size,
                              hipStream_t stream)
{
    const float* cl_h   = (const float*)d_in[0];
    const float* cl_w   = (const float*)d_in[1];
    const int*   cl_src = (const int*)d_in[2];
    const int*   cl_dst = (const int*)d_in[3];
    const int*   g_src  = (const int*)d_in[4];
    const int*   g_dst  = (const int*)d_in[5];
    const int*   g_et   = (const int*)d_in[6];
    const float* feats  = (const float*)d_in[7];
    const float* W_e    = (const float*)d_in[8];
    const float* b1     = (const float*)d_in[9];
    const float* e1     = (const float*)d_in[10];
    const float* b2     = (const float*)d_in[11];
    const float* e2     = (const float*)d_in[12];
    const float* W1a    = (const float*)d_in[13];
    const float* W2a    = (const float*)d_in[14];
    const float* W1b    = (const float*)d_in[15];
    const float* W2b    = (const float*)d_in[16];
    const float* Wp     = (const float*)d_in[17];
    const float* bp     = (const float*)d_in[18];
    const int ECL = in_sizes[1];
    const int E   = in_sizes[4];
    const int N   = in_sizes[7] / 64;

    char* w = (char*)d_ws;
    auto carve = [&](size_t bytes) {
        char* r = w;
        w += (bytes + 255) & ~(size_t)255;
        return r;
    };
    float* hW     = (float*)carve(32 * 64 * sizeof(float));
    float* sum_ew = (float*)carve((size_t)N * 64 * sizeof(float));
    int*   deg    = (int*)carve((size_t)N * sizeof(int));
    int*   off    = (int*)carve((size_t)(N + 1) * sizeof(int));
    int*   pos    = (int*)carve((size_t)N * sizeof(int));
    float* aggF   = (float*)carve((size_t)N * 64 * sizeof(float));
    float* x1     = (float*)carve((size_t)N * 64 * sizeof(float));
    size_t cntBytes = (size_t)N * 32 * sizeof(int);
    size_t srcBytes = (size_t)E * sizeof(int);
    int*   cnt    = (int*)carve(cntBytes > srcBytes ? cntBytes : srcBytes);
    int*   ssrc   = cnt;   // alias: scatter runs after sumew has consumed cnt

    hipMemsetAsync(cnt, 0, cntBytes, stream);

    agnn_kernel<<<1, 512, 0, stream>>>(cl_h, cl_w, cl_src, cl_dst, W_e,
                                       b1, e1, b2, e2, hW, ECL);
    hist_kernel<<<2048, 256, 0, stream>>>(g_dst, g_et, cnt, E);
    sumew_kernel<<<3200, 256, 0, stream>>>(cnt, hW, sum_ew, deg, N);
    scan_kernel<<<1, 1024, 0, stream>>>(deg, off, pos, N);
    scatter_kernel<<<2048, 256, 0, stream>>>(g_src, g_dst, pos, ssrc, E);
    spmm_kernel<<<(N + 3) / 4, 256, 0, stream>>>(feats, off, ssrc, aggF, N);
    gconv_kernel<<<(N + 63) / 64, 64, 0, stream>>>(feats, aggF, sum_ew,
                                                   W1a, W2a, x1, N, 0, Wp, bp);
    spmm_kernel<<<(N + 3) / 4, 256, 0, stream>>>(x1, off, ssrc, aggF, N);
    gconv_kernel<<<(N + 63) / 64, 64, 0, stream>>>(x1, aggF, sum_ew,
                                                   W1b, W2b, (float*)d_out, N, 1, Wp, bp);
}

// Round 4
// 485.891 us; speedup vs baseline: 2.1108x; 1.0395x over previous
//
#include <hip/hip_runtime.h>

// ---------------------------------------------------------------------------
// Pipeline:
//  1. agnn_kernel (1 block): 2x AGNN on 32-node line graph -> hW = h @ W_e [32,64]
//  2. hist_kernel: cnt[n][t] etype histogram (4-deep ILP, fire-and-forget atomics)
//  3. sumew_kernel: sum_ew[n][d] = sum_t cnt[n][t]*hW[t][d]; also emits deg[n]
//  4. scan_partial/root/apply: multi-block exclusive scan of deg -> off, pos
//  5. scatter_kernel: CSR-by-dst src list (4-deep ILP; atomicExch stores -> L2-side)
//  6. spmm_kernel: aggF[n] = sum over incoming edges of feat[src]
//  7. gconv_kernel: out = tanh(feat@W1 + (aggF - sum_ew)@W2), final layer fuses pred head
// ---------------------------------------------------------------------------

__device__ __forceinline__ unsigned ford_enc(float v) {
    unsigned b = __float_as_uint(v);
    return (b & 0x80000000u) ? ~b : (b | 0x80000000u);
}
__device__ __forceinline__ float ford_dec(unsigned k) {
    return __uint_as_float((k & 0x80000000u) ? (k ^ 0x80000000u) : ~k);
}

__global__ __launch_bounds__(512) void agnn_kernel(
    const float* __restrict__ cl_h, const float* __restrict__ cl_w,
    const int* __restrict__ cl_src, const int* __restrict__ cl_dst,
    const float* __restrict__ W_e,
    const float* __restrict__ pb1, const float* __restrict__ pe1,
    const float* __restrict__ pb2, const float* __restrict__ pe2,
    float* __restrict__ hW, int ECL)
{
    __shared__ float w_s[1024];
    __shared__ int   src_s[1024];
    __shared__ int   dst_s[1024];
    __shared__ float h[32][16];
    __shared__ float nh[32][16];
    __shared__ float p[1024];
    __shared__ float red[32][16];
    __shared__ float acc16[32][16][16];   // [t][j][f] aggregate partials, 32 KB
    __shared__ unsigned mI[32];
    __shared__ float m[32], ssum[32], nrm[32];
    const int tid = threadIdx.x;
    const int seg = tid >> 4, j = tid & 15;   // 16 threads per segment

    for (int e = tid; e < ECL; e += 512) {
        w_s[e] = cl_w[e]; src_s[e] = cl_src[e]; dst_s[e] = cl_dst[e];
    }
    h[tid >> 4][tid & 15] = cl_h[tid];        // 32*16 == 512
    __syncthreads();

    for (int layer = 0; layer < 2; ++layer) {
        const float beta = layer ? *pb2 : *pb1;
        const float eps  = layer ? *pe2 : *pe1;

        // ---- segment max over src: LDS atomicMax (order-independent => deterministic)
        if (tid < 32) mI[tid] = ford_enc(-3.4e38f);
        __syncthreads();
        for (int e = tid; e < ECL; e += 512)
            atomicMax(&mI[src_s[e]], ford_enc(beta * w_s[e]));
        __syncthreads();
        if (tid < 32) m[tid] = ford_dec(mI[tid]);
        __syncthreads();

        for (int e = tid; e < ECL; e += 512)
            p[e] = __expf(beta * w_s[e] - m[src_s[e]]);
        __syncthreads();

        // ---- segment sum: 16 fixed-order partials per segment (deterministic) ----
        {
            float s = 0.f;
            #pragma unroll 4
            for (int e = j; e < ECL; e += 16)
                s += (src_s[e] == seg) ? p[e] : 0.f;
            red[seg][j] = s;
        }
        __syncthreads();
        if (tid < 32) {
            float s = 0.f;
            #pragma unroll
            for (int k = 0; k < 16; ++k) s += red[tid][k];
            ssum[tid] = s;
            float q = 0.f;
            #pragma unroll
            for (int f = 0; f < 16; ++f) { float v = h[tid][f]; q += v * v; }
            nrm[tid] = fmaxf(sqrtf(q), 1e-12f);
        }
        __syncthreads();
        for (int e = tid; e < ECL; e += 512)
            p[e] = p[e] / ssum[src_s[e]];
        nh[tid >> 4][tid & 15] = h[tid >> 4][tid & 15] / nrm[tid >> 4];
        __syncthreads();

        // ---- aggregate: thread (t,j) scans e==j (mod 16), owns 16-float row ----
        {
            float facc[16];
            #pragma unroll
            for (int f = 0; f < 16; ++f) facc[f] = 0.f;
            #pragma unroll 4
            for (int e = j; e < ECL; e += 16) {
                if (dst_s[e] == seg) {
                    const float pe = p[e];
                    const float4* nhrow = reinterpret_cast<const float4*>(&nh[src_s[e]][0]);
                    const float4 a0 = nhrow[0], a1 = nhrow[1], a2 = nhrow[2], a3 = nhrow[3];
                    facc[0] += pe * a0.x; facc[1] += pe * a0.y; facc[2] += pe * a0.z; facc[3] += pe * a0.w;
                    facc[4] += pe * a1.x; facc[5] += pe * a1.y; facc[6] += pe * a1.z; facc[7] += pe * a1.w;
                    facc[8] += pe * a2.x; facc[9] += pe * a2.y; facc[10] += pe * a2.z; facc[11] += pe * a2.w;
                    facc[12] += pe * a3.x; facc[13] += pe * a3.y; facc[14] += pe * a3.z; facc[15] += pe * a3.w;
                }
            }
            #pragma unroll
            for (int f = 0; f < 16; ++f) acc16[seg][j][f] = facc[f];
        }
        __syncthreads();
        {
            const int t = tid >> 4, f = tid & 15;
            float a = 0.f;
            #pragma unroll
            for (int k = 0; k < 16; ++k) a += acc16[t][k][f];
            float v = (1.f + eps) * h[t][f] + a;
            h[t][f] = fmaxf(v, 0.f);   // only this thread touches h[t][f]
        }
        __syncthreads();
    }

    // hW[t][d] = sum_f h[t][f] * W_e[f][d]
    for (int o = tid; o < 2048; o += 512) {
        const int t = o >> 6, d = o & 63;
        float s = 0.f;
        #pragma unroll
        for (int f = 0; f < 16; ++f) s += h[t][f] * W_e[f * 64 + d];
        hW[o] = s;
    }
}

// 4 edges/thread: int4 index loads, 4 independent fire-and-forget atomics
__global__ __launch_bounds__(256) void hist_kernel(
    const int* __restrict__ dst, const int* __restrict__ et,
    int* __restrict__ cnt, int E)
{
    const int i = (blockIdx.x * 256 + threadIdx.x) * 4;
    if (i + 3 < E) {
        const int4 d = *reinterpret_cast<const int4*>(&dst[i]);
        const int4 t = *reinterpret_cast<const int4*>(&et[i]);
        atomicAdd(&cnt[d.x * 32 + t.x], 1);
        atomicAdd(&cnt[d.y * 32 + t.y], 1);
        atomicAdd(&cnt[d.z * 32 + t.z], 1);
        atomicAdd(&cnt[d.w * 32 + t.w], 1);
    } else {
        for (int k = i; k < E; ++k) atomicAdd(&cnt[dst[k] * 32 + et[k]], 1);
    }
}

// sum_ew[n][d] = sum_t cnt[n][t]*hW[t][d]; lane d==0 also writes deg[n]
__global__ __launch_bounds__(256) void sumew_kernel(
    const int* __restrict__ cnt, const float* __restrict__ hW,
    float* __restrict__ sum_ew, int* __restrict__ deg, int N)
{
    __shared__ float hWl[2048];
    for (int i = threadIdx.x; i < 2048; i += 256) hWl[i] = hW[i];
    __syncthreads();
    const int total = N * 64;
    for (int idx = blockIdx.x * 256 + threadIdx.x; idx < total; idx += gridDim.x * 256) {
        const int n = idx >> 6, d = idx & 63;
        float s = 0.f;
        int dg = 0;
        #pragma unroll
        for (int t = 0; t < 32; ++t) {
            const int c = cnt[n * 32 + t];      // wave-uniform per n -> broadcast
            s += (float)c * hWl[t * 64 + d];
            dg += c;
        }
        sum_ew[idx] = s;
        if (d == 0) deg[n] = dg;
    }
}

// ---- multi-block scan: tile = 2048 (512 threads x 4) ----
__global__ __launch_bounds__(512) void scan_partial(
    const int* __restrict__ deg, int* __restrict__ part, int N)
{
    __shared__ int wsum[8];
    const int tid = threadIdx.x, lane = tid & 63, wv = tid >> 6;
    const int i0 = blockIdx.x * 2048 + tid * 4;
    int t = 0;
    if (i0 + 3 < N) {
        const int4 v = *reinterpret_cast<const int4*>(&deg[i0]);
        t = v.x + v.y + v.z + v.w;
    } else {
        for (int k = i0; k < N && k < i0 + 4; ++k) t += deg[k];
    }
    #pragma unroll
    for (int s = 32; s >= 1; s >>= 1) t += __shfl_xor(t, s, 64);
    if (lane == 0) wsum[wv] = t;
    __syncthreads();
    if (tid == 0) {
        int s = 0;
        #pragma unroll
        for (int k = 0; k < 8; ++k) s += wsum[k];
        part[blockIdx.x] = s;
    }
}

__global__ __launch_bounds__(1024) void scan_root(
    const int* __restrict__ part, int* __restrict__ partx,
    int* __restrict__ off, int N, int P)
{
    __shared__ int wsum[16];
    const int tid = threadIdx.x, lane = tid & 63, wv = tid >> 6;
    const int v = (tid < P) ? part[tid] : 0;
    int x = v;
    #pragma unroll
    for (int s = 1; s < 64; s <<= 1) {
        const int t = __shfl_up(x, s, 64);
        if (lane >= s) x += t;
    }
    if (lane == 63) wsum[wv] = x;
    __syncthreads();
    if (wv == 0 && lane < 16) {
        int y = wsum[lane];
        #pragma unroll
        for (int s = 1; s < 16; s <<= 1) {
            const int t = __shfl_up(y, s, 64);
            if (lane >= s) y += t;
        }
        wsum[lane] = y;
    }
    __syncthreads();
    const int incl = ((wv == 0) ? 0 : wsum[wv - 1]) + x;
    if (tid < P) partx[tid] = incl - v;
    if (tid == P - 1) off[N] = incl;
}

__global__ __launch_bounds__(512) void scan_apply(
    const int* __restrict__ deg, const int* __restrict__ partx,
    int* __restrict__ off, int* __restrict__ pos, int N)
{
    __shared__ int wsum[8];
    const int tid = threadIdx.x, lane = tid & 63, wv = tid >> 6;
    const int i0 = blockIdx.x * 2048 + tid * 4;
    int v0 = 0, v1 = 0, v2 = 0, v3 = 0;
    if (i0 + 3 < N) {
        const int4 v = *reinterpret_cast<const int4*>(&deg[i0]);
        v0 = v.x; v1 = v.y; v2 = v.z; v3 = v.w;
    } else {
        if (i0 < N) v0 = deg[i0];
        if (i0 + 1 < N) v1 = deg[i0 + 1];
        if (i0 + 2 < N) v2 = deg[i0 + 2];
        if (i0 + 3 < N) v3 = deg[i0 + 3];
    }
    const int t = v0 + v1 + v2 + v3;
    int x = t;
    #pragma unroll
    for (int s = 1; s < 64; s <<= 1) {
        const int u = __shfl_up(x, s, 64);
        if (lane >= s) x += u;
    }
    if (lane == 63) wsum[wv] = x;
    __syncthreads();
    if (wv == 0 && lane < 8) {
        int y = wsum[lane];
        #pragma unroll
        for (int s = 1; s < 8; s <<= 1) {
            const int u = __shfl_up(y, s, 64);
            if (lane >= s) y += u;
        }
        wsum[lane] = y;
    }
    __syncthreads();
    const int base = partx[blockIdx.x] + ((wv == 0) ? 0 : wsum[wv - 1]) + (x - t);
    if (i0 + 3 < N) {
        const int4 o = make_int4(base, base + v0, base + v0 + v1, base + v0 + v1 + v2);
        *reinterpret_cast<int4*>(&off[i0]) = o;
        *reinterpret_cast<int4*>(&pos[i0]) = o;
    } else {
        int b = base;
        if (i0 < N)     { off[i0] = b; pos[i0] = b; b += v0; }
        if (i0 + 1 < N) { off[i0 + 1] = b; pos[i0 + 1] = b; b += v1; }
        if (i0 + 2 < N) { off[i0 + 2] = b; pos[i0 + 2] = b; b += v2; }
        if (i0 + 3 < N) { off[i0 + 3] = b; pos[i0 + 3] = b; }
    }
}

// 4 edges/thread; atomicExch store keeps ssrc lines in L2 (kills write-amp)
__global__ __launch_bounds__(256) void scatter_kernel(
    const int* __restrict__ src, const int* __restrict__ dst,
    int* __restrict__ pos, int* __restrict__ ssrc, int E)
{
    const int i = (blockIdx.x * 256 + threadIdx.x) * 4;
    if (i + 3 < E) {
        const int4 d = *reinterpret_cast<const int4*>(&dst[i]);
        const int4 s = *reinterpret_cast<const int4*>(&src[i]);
        const int p0 = atomicAdd(&pos[d.x], 1);
        const int p1 = atomicAdd(&pos[d.y], 1);
        const int p2 = atomicAdd(&pos[d.z], 1);
        const int p3 = atomicAdd(&pos[d.w], 1);
        atomicExch(&ssrc[p0], s.x);
        atomicExch(&ssrc[p1], s.y);
        atomicExch(&ssrc[p2], s.z);
        atomicExch(&ssrc[p3], s.w);
    } else {
        for (int k = i; k < E; ++k) {
            const int p = atomicAdd(&pos[dst[k]], 1);
            atomicExch(&ssrc[p], src[k]);
        }
    }
}

// one wave per destination node; lane = feature dim
__global__ __launch_bounds__(256) void spmm_kernel(
    const float* __restrict__ feat, const int* __restrict__ off,
    const int* __restrict__ ssrc, float* __restrict__ agg, int N)
{
    const int lane = threadIdx.x & 63;
    const int n = blockIdx.x * 4 + (threadIdx.x >> 6);
    if (n >= N) return;
    const int beg = off[n], end = off[n + 1];
    float acc = 0.f;
    int i = beg;
    for (; i + 8 <= end; i += 8) {
        int s[8];
        #pragma unroll
        for (int j = 0; j < 8; ++j) s[j] = ssrc[i + j];
        #pragma unroll
        for (int j = 0; j < 8; ++j) acc += feat[(size_t)s[j] * 64 + lane];
    }
    for (; i < end; ++i) acc += feat[(size_t)ssrc[i] * 64 + lane];
    agg[(size_t)n * 64 + lane] = acc;
}

// one node per lane; W rows are wave-uniform (scalar loads); fa transposed via LDS
__global__ __launch_bounds__(64) void gconv_kernel(
    const float* __restrict__ feat, const float* __restrict__ aggF,
    const float* __restrict__ sumew,
    const float* __restrict__ W1, const float* __restrict__ W2,
    float* __restrict__ outp, int N, int final_mode,
    const float* __restrict__ Wp, const float* __restrict__ bp)
{
    __shared__ float fa[64][33];   // stride 33 -> conflict-free column reads
    const int lane = threadIdx.x;
    const int n0 = blockIdx.x * 64;
    const int n = n0 + lane;
    const bool valid = n < N;

    float acc[64];
    #pragma unroll
    for (int d = 0; d < 64; ++d) acc[d] = 0.f;

    for (int half = 0; half < 2; ++half) {
        const float* __restrict__ W = half ? W2 : W1;
        for (int kc = 0; kc < 2; ++kc) {
            __syncthreads();
            #pragma unroll
            for (int it = 0; it < 8; ++it) {
                const int idx = it * 64 + lane;
                const int row = idx >> 3;      // 0..63
                const int c4  = idx & 7;       // 0..7
                const int rn = n0 + row;
                float4 v = make_float4(0.f, 0.f, 0.f, 0.f);
                if (rn < N) {
                    const size_t base = (size_t)rn * 64 + kc * 32 + c4 * 4;
                    if (half == 0) {
                        v = *reinterpret_cast<const float4*>(&feat[base]);
                    } else {
                        float4 a = *reinterpret_cast<const float4*>(&aggF[base]);
                        float4 s = *reinterpret_cast<const float4*>(&sumew[base]);
                        v = make_float4(a.x - s.x, a.y - s.y, a.z - s.z, a.w - s.w);
                    }
                }
                fa[row][c4 * 4 + 0] = v.x;
                fa[row][c4 * 4 + 1] = v.y;
                fa[row][c4 * 4 + 2] = v.z;
                fa[row][c4 * 4 + 3] = v.w;
            }
            __syncthreads();
            for (int k8 = 0; k8 < 32; ++k8) {
                const float fval = fa[lane][k8];
                const float* wrow = &W[(size_t)(kc * 32 + k8) * 64];
                #pragma unroll
                for (int d4 = 0; d4 < 16; ++d4) {
                    float4 w = *reinterpret_cast<const float4*>(&wrow[d4 * 4]);
                    acc[d4 * 4 + 0] += fval * w.x;
                    acc[d4 * 4 + 1] += fval * w.y;
                    acc[d4 * 4 + 2] += fval * w.z;
                    acc[d4 * 4 + 3] += fval * w.w;
                }
            }
        }
    }

    // tanh(x) = 1 - 2/(e^{2x}+1)  (inf-safe)
    #pragma unroll
    for (int d = 0; d < 64; ++d) {
        const float e2 = __expf(2.f * acc[d]);
        acc[d] = 1.f - 2.f / (e2 + 1.f);
    }

    if (!final_mode) {
        if (valid) {
            #pragma unroll
            for (int d4 = 0; d4 < 16; ++d4) {
                float4 v = make_float4(acc[d4 * 4], acc[d4 * 4 + 1],
                                       acc[d4 * 4 + 2], acc[d4 * 4 + 3]);
                *reinterpret_cast<float4*>(&outp[(size_t)n * 64 + d4 * 4]) = v;
            }
        }
    } else {
        float o[16];
        #pragma unroll
        for (int c = 0; c < 16; ++c) o[c] = bp[c];
        #pragma unroll
        for (int d = 0; d < 64; ++d) {
            const float t = acc[d];
            #pragma unroll
            for (int c = 0; c < 16; ++c) o[c] += t * Wp[d * 16 + c];
        }
        if (valid) {
            #pragma unroll
            for (int c4 = 0; c4 < 4; ++c4) {
                float4 v = make_float4(o[c4 * 4], o[c4 * 4 + 1],
                                       o[c4 * 4 + 2], o[c4 * 4 + 3]);
                *reinterpret_cast<float4*>(&outp[(size_t)n * 16 + c4 * 4]) = v;
            }
        }
    }
}

extern "C" void kernel_launch(void* const* d_in, const int* in_sizes, int n_in,
                              void* d_out, int out_size, void* d_ws, size_t ws_size,
                              hipStream_t stream)
{
    const float* cl_h   = (const float*)d_in[0];
    const float* cl_w   = (const float*)d_in[1];
    const int*   cl_src = (const int*)d_in[2];
    const int*   cl_dst = (const int*)d_in[3];
    const int*   g_src  = (const int*)d_in[4];
    const int*   g_dst  = (const int*)d_in[5];
    const int*   g_et   = (const int*)d_in[6];
    const float* feats  = (const float*)d_in[7];
    const float* W_e    = (const float*)d_in[8];
    const float* b1     = (const float*)d_in[9];
    const float* e1     = (const float*)d_in[10];
    const float* b2     = (const float*)d_in[11];
    const float* e2     = (const float*)d_in[12];
    const float* W1a    = (const float*)d_in[13];
    const float* W2a    = (const float*)d_in[14];
    const float* W1b    = (const float*)d_in[15];
    const float* W2b    = (const float*)d_in[16];
    const float* Wp     = (const float*)d_in[17];
    const float* bp     = (const float*)d_in[18];
    const int ECL = in_sizes[1];
    const int E   = in_sizes[4];
    const int N   = in_sizes[7] / 64;

    char* w = (char*)d_ws;
    auto carve = [&](size_t bytes) {
        char* r = w;
        w += (bytes + 255) & ~(size_t)255;
        return r;
    };
    float* hW     = (float*)carve(32 * 64 * sizeof(float));
    float* sum_ew = (float*)carve((size_t)N * 64 * sizeof(float));
    int*   deg    = (int*)carve((size_t)N * sizeof(int));
    int*   off    = (int*)carve((size_t)(N + 1) * sizeof(int));
    int*   pos    = (int*)carve((size_t)N * sizeof(int));
    int*   part   = (int*)carve(1024 * sizeof(int));
    int*   partx  = (int*)carve(1024 * sizeof(int));
    float* aggF   = (float*)carve((size_t)N * 64 * sizeof(float));
    float* x1     = (float*)carve((size_t)N * 64 * sizeof(float));
    size_t cntBytes = (size_t)N * 32 * sizeof(int);
    size_t srcBytes = (size_t)E * sizeof(int);
    int*   cnt    = (int*)carve(cntBytes > srcBytes ? cntBytes : srcBytes);
    int*   ssrc   = cnt;   // alias: scatter runs after sumew has consumed cnt

    const int nparts = (N + 2047) / 2048;

    hipMemsetAsync(cnt, 0, cntBytes, stream);

    agnn_kernel<<<1, 512, 0, stream>>>(cl_h, cl_w, cl_src, cl_dst, W_e,
                                       b1, e1, b2, e2, hW, ECL);
    hist_kernel<<<(E / 4 + 255) / 256, 256, 0, stream>>>(g_dst, g_et, cnt, E);
    sumew_kernel<<<3200, 256, 0, stream>>>(cnt, hW, sum_ew, deg, N);
    scan_partial<<<nparts, 512, 0, stream>>>(deg, part, N);
    scan_root<<<1, 1024, 0, stream>>>(part, partx, off, N, nparts);
    scan_apply<<<nparts, 512, 0, stream>>>(deg, partx, off, pos, N);
    scatter_kernel<<<(E / 4 + 255) / 256, 256, 0, stream>>>(g_src, g_dst, pos, ssrc, E);
    spmm_kernel<<<(N + 3) / 4, 256, 0, stream>>>(feats, off, ssrc, aggF, N);
    gconv_kernel<<<(N + 63) / 64, 64, 0, stream>>>(feats, aggF, sum_ew,
                                                   W1a, W2a, x1, N, 0, Wp, bp);
    spmm_kernel<<<(N + 3) / 4, 256, 0, stream>>>(x1, off, ssrc, aggF, N);
    gconv_kernel<<<(N + 63) / 64, 64, 0, stream>>>(x1, aggF, sum_ew,
                                                   W1b, W2b, (float*)d_out, N, 1, Wp, bp);
}

// Round 5
// 311.491 us; speedup vs baseline: 3.2926x; 1.5599x over previous
//
#include <hip/hip_runtime.h>

// ---------------------------------------------------------------------------
// Pipeline (assumes N <= 65536, NCL <= 32: src and etype pack into one u32):
//  1. agnn_kernel (1 block): 2x AGNN on 32-node line graph -> hW = h @ W_e [32,64]
//  2. bucket_count:  per-block LDS hist of dst>>8 -> global bucket counts
//  3. bucket_scan (1 block): exclusive scan of 256 bucket counts -> bbase, bcur
//  4. bucket_scatter: LDS-staged binned scatter of packed (et,dstlow,src) -> etmp
//     (writes are bucket-contiguous runs => coalesced; 38K global atomics total)
//  5. csr_kernel (1 block/bucket): fine CSR within 32KB L2-hot window -> off, ssrc
//  6. spmm_kernel: agg[n] = sum_{e: dst=n} (feat[src_e] - hW[et_e])   (hW in LDS)
//  7. gconv_kernel: out = tanh(feat@W1 + agg@W2), final layer fuses pred head
// ---------------------------------------------------------------------------

#define TILE 8192

__device__ __forceinline__ unsigned ford_enc(float v) {
    unsigned b = __float_as_uint(v);
    return (b & 0x80000000u) ? ~b : (b | 0x80000000u);
}
__device__ __forceinline__ float ford_dec(unsigned k) {
    return __uint_as_float((k & 0x80000000u) ? (k ^ 0x80000000u) : ~k);
}

__global__ __launch_bounds__(512) void agnn_kernel(
    const float* __restrict__ cl_h, const float* __restrict__ cl_w,
    const int* __restrict__ cl_src, const int* __restrict__ cl_dst,
    const float* __restrict__ W_e,
    const float* __restrict__ pb1, const float* __restrict__ pe1,
    const float* __restrict__ pb2, const float* __restrict__ pe2,
    float* __restrict__ hW, int ECL)
{
    __shared__ float w_s[1024];
    __shared__ int   src_s[1024];
    __shared__ int   dst_s[1024];
    __shared__ float h[32][16];
    __shared__ float nh[32][16];
    __shared__ float p[1024];
    __shared__ float red[32][16];
    __shared__ float acc16[32][16][16];
    __shared__ unsigned mI[32];
    __shared__ float m[32], ssum[32], nrm[32];
    const int tid = threadIdx.x;
    const int seg = tid >> 4, j = tid & 15;

    for (int e = tid; e < ECL; e += 512) {
        w_s[e] = cl_w[e]; src_s[e] = cl_src[e]; dst_s[e] = cl_dst[e];
    }
    h[tid >> 4][tid & 15] = cl_h[tid];
    __syncthreads();

    for (int layer = 0; layer < 2; ++layer) {
        const float beta = layer ? *pb2 : *pb1;
        const float eps  = layer ? *pe2 : *pe1;

        if (tid < 32) mI[tid] = ford_enc(-3.4e38f);
        __syncthreads();
        for (int e = tid; e < ECL; e += 512)
            atomicMax(&mI[src_s[e]], ford_enc(beta * w_s[e]));
        __syncthreads();
        if (tid < 32) m[tid] = ford_dec(mI[tid]);
        __syncthreads();

        for (int e = tid; e < ECL; e += 512)
            p[e] = __expf(beta * w_s[e] - m[src_s[e]]);
        __syncthreads();

        {
            float s = 0.f;
            #pragma unroll 4
            for (int e = j; e < ECL; e += 16)
                s += (src_s[e] == seg) ? p[e] : 0.f;
            red[seg][j] = s;
        }
        __syncthreads();
        if (tid < 32) {
            float s = 0.f;
            #pragma unroll
            for (int k = 0; k < 16; ++k) s += red[tid][k];
            ssum[tid] = s;
            float q = 0.f;
            #pragma unroll
            for (int f = 0; f < 16; ++f) { float v = h[tid][f]; q += v * v; }
            nrm[tid] = fmaxf(sqrtf(q), 1e-12f);
        }
        __syncthreads();
        for (int e = tid; e < ECL; e += 512)
            p[e] = p[e] / ssum[src_s[e]];
        nh[tid >> 4][tid & 15] = h[tid >> 4][tid & 15] / nrm[tid >> 4];
        __syncthreads();

        {
            float facc[16];
            #pragma unroll
            for (int f = 0; f < 16; ++f) facc[f] = 0.f;
            #pragma unroll 4
            for (int e = j; e < ECL; e += 16) {
                if (dst_s[e] == seg) {
                    const float pe = p[e];
                    const float4* nhrow = reinterpret_cast<const float4*>(&nh[src_s[e]][0]);
                    const float4 a0 = nhrow[0], a1 = nhrow[1], a2 = nhrow[2], a3 = nhrow[3];
                    facc[0] += pe * a0.x; facc[1] += pe * a0.y; facc[2] += pe * a0.z; facc[3] += pe * a0.w;
                    facc[4] += pe * a1.x; facc[5] += pe * a1.y; facc[6] += pe * a1.z; facc[7] += pe * a1.w;
                    facc[8] += pe * a2.x; facc[9] += pe * a2.y; facc[10] += pe * a2.z; facc[11] += pe * a2.w;
                    facc[12] += pe * a3.x; facc[13] += pe * a3.y; facc[14] += pe * a3.z; facc[15] += pe * a3.w;
                }
            }
            #pragma unroll
            for (int f = 0; f < 16; ++f) acc16[seg][j][f] = facc[f];
        }
        __syncthreads();
        {
            const int t = tid >> 4, f = tid & 15;
            float a = 0.f;
            #pragma unroll
            for (int k = 0; k < 16; ++k) a += acc16[t][k][f];
            float v = (1.f + eps) * h[t][f] + a;
            h[t][f] = fmaxf(v, 0.f);
        }
        __syncthreads();
    }

    for (int o = tid; o < 2048; o += 512) {
        const int t = o >> 6, d = o & 63;
        float s = 0.f;
        #pragma unroll
        for (int f = 0; f < 16; ++f) s += h[t][f] * W_e[f * 64 + d];
        hW[o] = s;
    }
}

__global__ __launch_bounds__(256) void bucket_count(
    const int* __restrict__ dst, int* __restrict__ bcnt, int E)
{
    __shared__ int lh[256];
    const int tid = threadIdx.x;
    lh[tid] = 0;
    __syncthreads();
    const int base = blockIdx.x * TILE;
    #pragma unroll
    for (int it = 0; it < 8; ++it) {
        const int i = base + (it * 256 + tid) * 4;
        if (i + 3 < E) {
            const int4 d = *reinterpret_cast<const int4*>(&dst[i]);
            atomicAdd(&lh[d.x >> 8], 1); atomicAdd(&lh[d.y >> 8], 1);
            atomicAdd(&lh[d.z >> 8], 1); atomicAdd(&lh[d.w >> 8], 1);
        } else {
            for (int k = i; k < E && k < i + 4; ++k) atomicAdd(&lh[dst[k] >> 8], 1);
        }
    }
    __syncthreads();
    if (lh[tid]) atomicAdd(&bcnt[tid], lh[tid]);
}

__global__ __launch_bounds__(256) void bucket_scan(
    const int* __restrict__ bcnt, int* __restrict__ bbase, int* __restrict__ bcur)
{
    __shared__ int ws[4];
    const int tid = threadIdx.x, lane = tid & 63, wv = tid >> 6;
    const int v = bcnt[tid];
    int x = v;
    #pragma unroll
    for (int s = 1; s < 64; s <<= 1) { const int t = __shfl_up(x, s, 64); if (lane >= s) x += t; }
    if (lane == 63) ws[wv] = x;
    __syncthreads();
    if (tid == 0) { int a = ws[0]; ws[0] = 0; for (int k = 1; k < 4; ++k) { const int b = ws[k]; ws[k] = a; a += b; } }
    __syncthreads();
    const int excl = ws[wv] + x - v;
    bbase[tid] = excl; bcur[tid] = excl;
    if (tid == 255) bbase[256] = excl + v;
}

__global__ __launch_bounds__(256) void bucket_scatter(
    const int* __restrict__ src, const int* __restrict__ dst, const int* __restrict__ et,
    int* __restrict__ bcur, unsigned* __restrict__ etmp, int E)
{
    __shared__ int lh[256], lofs[256], lcur[256], gbase[256];
    __shared__ int ws[4];
    __shared__ unsigned stage[TILE];
    __shared__ unsigned char sbk[TILE];
    const int tid = threadIdx.x, lane = tid & 63, wv = tid >> 6;
    lh[tid] = 0;
    __syncthreads();
    const int base = blockIdx.x * TILE;
    #pragma unroll
    for (int it = 0; it < 8; ++it) {
        const int i = base + (it * 256 + tid) * 4;
        if (i + 3 < E) {
            const int4 d = *reinterpret_cast<const int4*>(&dst[i]);
            atomicAdd(&lh[d.x >> 8], 1); atomicAdd(&lh[d.y >> 8], 1);
            atomicAdd(&lh[d.z >> 8], 1); atomicAdd(&lh[d.w >> 8], 1);
        } else {
            for (int k = i; k < E && k < i + 4; ++k) atomicAdd(&lh[dst[k] >> 8], 1);
        }
    }
    __syncthreads();
    {
        const int v = lh[tid];
        int x = v;
        #pragma unroll
        for (int s = 1; s < 64; s <<= 1) { const int t = __shfl_up(x, s, 64); if (lane >= s) x += t; }
        if (lane == 63) ws[wv] = x;
        __syncthreads();
        if (tid == 0) { int a = ws[0]; ws[0] = 0; for (int k = 1; k < 4; ++k) { const int b = ws[k]; ws[k] = a; a += b; } }
        __syncthreads();
        const int excl = ws[wv] + x - v;
        lofs[tid] = excl; lcur[tid] = excl;
        if (v) gbase[tid] = atomicAdd(&bcur[tid], v);
    }
    __syncthreads();
    #pragma unroll
    for (int it = 0; it < 8; ++it) {
        const int i = base + (it * 256 + tid) * 4;
        if (i + 3 < E) {
            const int4 d  = *reinterpret_cast<const int4*>(&dst[i]);
            const int4 s4 = *reinterpret_cast<const int4*>(&src[i]);
            const int4 t4 = *reinterpret_cast<const int4*>(&et[i]);
            int b, r;
            b = d.x >> 8; r = atomicAdd(&lcur[b], 1);
            stage[r] = (unsigned)s4.x | ((unsigned)(d.x & 255) << 16) | ((unsigned)t4.x << 24); sbk[r] = (unsigned char)b;
            b = d.y >> 8; r = atomicAdd(&lcur[b], 1);
            stage[r] = (unsigned)s4.y | ((unsigned)(d.y & 255) << 16) | ((unsigned)t4.y << 24); sbk[r] = (unsigned char)b;
            b = d.z >> 8; r = atomicAdd(&lcur[b], 1);
            stage[r] = (unsigned)s4.z | ((unsigned)(d.z & 255) << 16) | ((unsigned)t4.z << 24); sbk[r] = (unsigned char)b;
            b = d.w >> 8; r = atomicAdd(&lcur[b], 1);
            stage[r] = (unsigned)s4.w | ((unsigned)(d.w & 255) << 16) | ((unsigned)t4.w << 24); sbk[r] = (unsigned char)b;
        } else {
            for (int k = i; k < E && k < i + 4; ++k) {
                const int b = dst[k] >> 8;
                const int r = atomicAdd(&lcur[b], 1);
                stage[r] = (unsigned)src[k] | ((unsigned)(dst[k] & 255) << 16) | ((unsigned)et[k] << 24);
                sbk[r] = (unsigned char)b;
            }
        }
    }
    __syncthreads();
    const int tot = lofs[255] + lh[255];
    for (int i = tid; i < tot; i += 256) {
        const int b = sbk[i];
        etmp[gbase[b] + (i - lofs[b])] = stage[i];
    }
}

// one block per bucket: fine CSR within the bucket's contiguous edge range
__global__ __launch_bounds__(256) void csr_kernel(
    const unsigned* __restrict__ etmp, const int* __restrict__ bbase,
    int* __restrict__ off, unsigned* __restrict__ ssrc, int N, int NB)
{
    __shared__ int lh[256], lofs[256], lcur[256];
    __shared__ int ws[4];
    const int tid = threadIdx.x, lane = tid & 63, wv = tid >> 6;
    const int b = blockIdx.x;
    const int s = bbase[b], e = bbase[b + 1];
    lh[tid] = 0;
    __syncthreads();
    for (int i = s + tid; i < e; i += 256)
        atomicAdd(&lh[(etmp[i] >> 16) & 255], 1);
    __syncthreads();
    {
        const int v = lh[tid];
        int x = v;
        #pragma unroll
        for (int ss = 1; ss < 64; ss <<= 1) { const int t = __shfl_up(x, ss, 64); if (lane >= ss) x += t; }
        if (lane == 63) ws[wv] = x;
        __syncthreads();
        if (tid == 0) { int a = ws[0]; ws[0] = 0; for (int k = 1; k < 4; ++k) { const int c = ws[k]; ws[k] = a; a += c; } }
        __syncthreads();
        const int excl = ws[wv] + x - v;
        lofs[tid] = excl; lcur[tid] = excl;
    }
    __syncthreads();
    const int n0 = b << 8;
    if (n0 + tid < N) off[n0 + tid] = s + lofs[tid];
    if (b == NB - 1 && tid == 0) off[N] = e;
    for (int i = s + tid; i < e; i += 256) {
        const unsigned pp = etmp[i];
        const int dl = (pp >> 16) & 255;
        const int r = atomicAdd(&lcur[dl], 1);
        ssrc[s + r] = pp;
    }
}

// agg[n] = sum over incoming edges (feat[src] - hW[et]); wave per node, lane = dim
__global__ __launch_bounds__(256) void spmm_kernel(
    const float* __restrict__ feat, const float* __restrict__ hW,
    const int* __restrict__ off, const unsigned* __restrict__ ssrc,
    float* __restrict__ agg, int N)
{
    __shared__ float hWl[2048];
    for (int i = threadIdx.x; i < 2048; i += 256) hWl[i] = hW[i];
    __syncthreads();
    const int lane = threadIdx.x & 63;
    const int n = blockIdx.x * 4 + (threadIdx.x >> 6);
    if (n >= N) return;
    const int beg = off[n], end = off[n + 1];
    float acc = 0.f;
    int i = beg;
    for (; i + 8 <= end; i += 8) {
        unsigned pp[8];
        #pragma unroll
        for (int j = 0; j < 8; ++j) pp[j] = ssrc[i + j];
        #pragma unroll
        for (int j = 0; j < 8; ++j) acc += feat[(size_t)(pp[j] & 0xFFFFu) * 64 + lane];
        #pragma unroll
        for (int j = 0; j < 8; ++j) acc -= hWl[(pp[j] >> 24) * 64 + lane];
    }
    for (; i < end; ++i) {
        const unsigned pp = ssrc[i];
        acc += feat[(size_t)(pp & 0xFFFFu) * 64 + lane] - hWl[(pp >> 24) * 64 + lane];
    }
    agg[(size_t)n * 64 + lane] = acc;
}

// one node per lane; W rows wave-uniform; fa transposed via LDS
__global__ __launch_bounds__(64) void gconv_kernel(
    const float* __restrict__ feat, const float* __restrict__ aggF,
    const float* __restrict__ W1, const float* __restrict__ W2,
    float* __restrict__ outp, int N, int final_mode,
    const float* __restrict__ Wp, const float* __restrict__ bp)
{
    __shared__ float fa[64][33];
    const int lane = threadIdx.x;
    const int n0 = blockIdx.x * 64;
    const int n = n0 + lane;
    const bool valid = n < N;

    float acc[64];
    #pragma unroll
    for (int d = 0; d < 64; ++d) acc[d] = 0.f;

    for (int half = 0; half < 2; ++half) {
        const float* __restrict__ X = half ? aggF : feat;
        const float* __restrict__ W = half ? W2 : W1;
        for (int kc = 0; kc < 2; ++kc) {
            __syncthreads();
            #pragma unroll
            for (int it = 0; it < 8; ++it) {
                const int idx = it * 64 + lane;
                const int row = idx >> 3;
                const int c4  = idx & 7;
                const int rn = n0 + row;
                float4 v = make_float4(0.f, 0.f, 0.f, 0.f);
                if (rn < N)
                    v = *reinterpret_cast<const float4*>(&X[(size_t)rn * 64 + kc * 32 + c4 * 4]);
                fa[row][c4 * 4 + 0] = v.x;
                fa[row][c4 * 4 + 1] = v.y;
                fa[row][c4 * 4 + 2] = v.z;
                fa[row][c4 * 4 + 3] = v.w;
            }
            __syncthreads();
            for (int k8 = 0; k8 < 32; ++k8) {
                const float fval = fa[lane][k8];
                const float* wrow = &W[(size_t)(kc * 32 + k8) * 64];
                #pragma unroll
                for (int d4 = 0; d4 < 16; ++d4) {
                    const float4 w = *reinterpret_cast<const float4*>(&wrow[d4 * 4]);
                    acc[d4 * 4 + 0] += fval * w.x;
                    acc[d4 * 4 + 1] += fval * w.y;
                    acc[d4 * 4 + 2] += fval * w.z;
                    acc[d4 * 4 + 3] += fval * w.w;
                }
            }
        }
    }

    #pragma unroll
    for (int d = 0; d < 64; ++d) {
        const float e2 = __expf(2.f * acc[d]);
        acc[d] = 1.f - 2.f / (e2 + 1.f);
    }

    if (!final_mode) {
        if (valid) {
            #pragma unroll
            for (int d4 = 0; d4 < 16; ++d4) {
                const float4 v = make_float4(acc[d4 * 4], acc[d4 * 4 + 1],
                                             acc[d4 * 4 + 2], acc[d4 * 4 + 3]);
                *reinterpret_cast<float4*>(&outp[(size_t)n * 64 + d4 * 4]) = v;
            }
        }
    } else {
        float o[16];
        #pragma unroll
        for (int c = 0; c < 16; ++c) o[c] = bp[c];
        #pragma unroll
        for (int d = 0; d < 64; ++d) {
            const float t = acc[d];
            #pragma unroll
            for (int c = 0; c < 16; ++c) o[c] += t * Wp[d * 16 + c];
        }
        if (valid) {
            #pragma unroll
            for (int c4 = 0; c4 < 4; ++c4) {
                const float4 v = make_float4(o[c4 * 4], o[c4 * 4 + 1],
                                             o[c4 * 4 + 2], o[c4 * 4 + 3]);
                *reinterpret_cast<float4*>(&outp[(size_t)n * 16 + c4 * 4]) = v;
            }
        }
    }
}

extern "C" void kernel_launch(void* const* d_in, const int* in_sizes, int n_in,
                              void* d_out, int out_size, void* d_ws, size_t ws_size,
                              hipStream_t stream)
{
    const float* cl_h   = (const float*)d_in[0];
    const float* cl_w   = (const float*)d_in[1];
    const int*   cl_src = (const int*)d_in[2];
    const int*   cl_dst = (const int*)d_in[3];
    const int*   g_src  = (const int*)d_in[4];
    const int*   g_dst  = (const int*)d_in[5];
    const int*   g_et   = (const int*)d_in[6];
    const float* feats  = (const float*)d_in[7];
    const float* W_e    = (const float*)d_in[8];
    const float* b1     = (const float*)d_in[9];
    const float* e1     = (const float*)d_in[10];
    const float* b2     = (const float*)d_in[11];
    const float* e2     = (const float*)d_in[12];
    const float* W1a    = (const float*)d_in[13];
    const float* W2a    = (const float*)d_in[14];
    const float* W1b    = (const float*)d_in[15];
    const float* W2b    = (const float*)d_in[16];
    const float* Wp     = (const float*)d_in[17];
    const float* bp     = (const float*)d_in[18];
    const int ECL = in_sizes[1];
    const int E   = in_sizes[4];
    const int N   = in_sizes[7] / 64;
    const int NB  = (N + 255) >> 8;

    char* w = (char*)d_ws;
    auto carve = [&](size_t bytes) {
        char* r = w;
        w += (bytes + 255) & ~(size_t)255;
        return r;
    };
    float*    hW    = (float*)carve(32 * 64 * sizeof(float));
    int*      off   = (int*)carve((size_t)(N + 1) * sizeof(int));
    int*      bcnt  = (int*)carve(256 * sizeof(int));
    int*      bbase = (int*)carve(257 * sizeof(int));
    int*      bcur  = (int*)carve(256 * sizeof(int));
    unsigned* etmp  = (unsigned*)carve((size_t)E * sizeof(unsigned));
    unsigned* ssrc  = (unsigned*)carve((size_t)E * sizeof(unsigned));
    float*    aggF  = (float*)carve((size_t)N * 64 * sizeof(float));
    float*    x1    = (float*)carve((size_t)N * 64 * sizeof(float));

    const int nblk = (E + TILE - 1) / TILE;

    hipMemsetAsync(bcnt, 0, 256 * sizeof(int), stream);

    agnn_kernel<<<1, 512, 0, stream>>>(cl_h, cl_w, cl_src, cl_dst, W_e,
                                       b1, e1, b2, e2, hW, ECL);
    bucket_count<<<nblk, 256, 0, stream>>>(g_dst, bcnt, E);
    bucket_scan<<<1, 256, 0, stream>>>(bcnt, bbase, bcur);
    bucket_scatter<<<nblk, 256, 0, stream>>>(g_src, g_dst, g_et, bcur, etmp, E);
    csr_kernel<<<NB, 256, 0, stream>>>(etmp, bbase, off, ssrc, N, NB);
    spmm_kernel<<<(N + 3) / 4, 256, 0, stream>>>(feats, hW, off, ssrc, aggF, N);
    gconv_kernel<<<(N + 63) / 64, 64, 0, stream>>>(feats, aggF, W1a, W2a, x1, N, 0, Wp, bp);
    spmm_kernel<<<(N + 3) / 4, 256, 0, stream>>>(x1, hW, off, ssrc, aggF, N);
    gconv_kernel<<<(N + 63) / 64, 64, 0, stream>>>(x1, aggF, W1b, W2b, (float*)d_out, N, 1, Wp, bp);
}

// Round 7
// 257.808 us; speedup vs baseline: 3.9782x; 1.2082x over previous
//
#include <hip/hip_runtime.h>

// ---------------------------------------------------------------------------
// Pipeline (N <= 65536, NCL <= 32):
//  1. agnn_kernel (1 block): 2x AGNN on line graph -> hW = h @ W_e [32,64] fp32
//  2. tobf16: feats fp32 -> fb16 (bf16 rows for the random gather only)
//  3. bucket_count/scan/scatter + csr: 2-level counting sort -> CSR (off, ssrc)
//     packed edge word: et<<24 | dst_low<<16 | src
//  4. spmm: aggF[n] = sum_in (gather_bf16[src] - hW[et]), fp32 accum, fp32 out
//  5. gconv: 4 threads/node x 16 outs; X=[Xf|Af] fp32 staged in LDS (XOR-swizzled),
//     W=[W1;W2] fp32 in LDS; out = tanh(X@W). Layer1 writes x1f (fp32) + x16 (bf16);
//     layer2 fuses pred head -> d_out fp32.
// ---------------------------------------------------------------------------

#define TILE 8192

typedef __attribute__((ext_vector_type(8))) unsigned short us8;

__device__ __forceinline__ float b2f(unsigned short h) {
    return __uint_as_float(((unsigned)h) << 16);
}
__device__ __forceinline__ unsigned short f2b(float f) {
    const unsigned u = __float_as_uint(f);
    return (unsigned short)((u + 0x7FFFu + ((u >> 16) & 1u)) >> 16);
}

__device__ __forceinline__ unsigned ford_enc(float v) {
    unsigned b = __float_as_uint(v);
    return (b & 0x80000000u) ? ~b : (b | 0x80000000u);
}
__device__ __forceinline__ float ford_dec(unsigned k) {
    return __uint_as_float((k & 0x80000000u) ? (k ^ 0x80000000u) : ~k);
}

__global__ __launch_bounds__(512) void agnn_kernel(
    const float* __restrict__ cl_h, const float* __restrict__ cl_w,
    const int* __restrict__ cl_src, const int* __restrict__ cl_dst,
    const float* __restrict__ W_e,
    const float* __restrict__ pb1, const float* __restrict__ pe1,
    const float* __restrict__ pb2, const float* __restrict__ pe2,
    float* __restrict__ hW, int ECL)
{
    __shared__ float w_s[1024];
    __shared__ int   src_s[1024];
    __shared__ int   dst_s[1024];
    __shared__ float h[32][16];
    __shared__ float nh[32][16];
    __shared__ float p[1024];
    __shared__ float red[32][16];
    __shared__ float acc16[32][16][16];
    __shared__ unsigned mI[32];
    __shared__ float m[32], ssum[32], nrm[32];
    const int tid = threadIdx.x;
    const int seg = tid >> 4, j = tid & 15;

    for (int e = tid; e < ECL; e += 512) {
        w_s[e] = cl_w[e]; src_s[e] = cl_src[e]; dst_s[e] = cl_dst[e];
    }
    h[tid >> 4][tid & 15] = cl_h[tid];
    __syncthreads();

    for (int layer = 0; layer < 2; ++layer) {
        const float beta = layer ? *pb2 : *pb1;
        const float eps  = layer ? *pe2 : *pe1;

        if (tid < 32) mI[tid] = ford_enc(-3.4e38f);
        __syncthreads();
        for (int e = tid; e < ECL; e += 512)
            atomicMax(&mI[src_s[e]], ford_enc(beta * w_s[e]));
        __syncthreads();
        if (tid < 32) m[tid] = ford_dec(mI[tid]);
        __syncthreads();

        for (int e = tid; e < ECL; e += 512)
            p[e] = __expf(beta * w_s[e] - m[src_s[e]]);
        __syncthreads();

        {
            float s = 0.f;
            #pragma unroll 4
            for (int e = j; e < ECL; e += 16)
                s += (src_s[e] == seg) ? p[e] : 0.f;
            red[seg][j] = s;
        }
        __syncthreads();
        if (tid < 32) {
            float s = 0.f;
            #pragma unroll
            for (int k = 0; k < 16; ++k) s += red[tid][k];
            ssum[tid] = s;
            float q = 0.f;
            #pragma unroll
            for (int f = 0; f < 16; ++f) { float v = h[tid][f]; q += v * v; }
            nrm[tid] = fmaxf(sqrtf(q), 1e-12f);
        }
        __syncthreads();
        for (int e = tid; e < ECL; e += 512)
            p[e] = p[e] / ssum[src_s[e]];
        nh[tid >> 4][tid & 15] = h[tid >> 4][tid & 15] / nrm[tid >> 4];
        __syncthreads();

        {
            float facc[16];
            #pragma unroll
            for (int f = 0; f < 16; ++f) facc[f] = 0.f;
            #pragma unroll 4
            for (int e = j; e < ECL; e += 16) {
                if (dst_s[e] == seg) {
                    const float pe = p[e];
                    const float4* nhrow = reinterpret_cast<const float4*>(&nh[src_s[e]][0]);
                    const float4 a0 = nhrow[0], a1 = nhrow[1], a2 = nhrow[2], a3 = nhrow[3];
                    facc[0] += pe * a0.x; facc[1] += pe * a0.y; facc[2] += pe * a0.z; facc[3] += pe * a0.w;
                    facc[4] += pe * a1.x; facc[5] += pe * a1.y; facc[6] += pe * a1.z; facc[7] += pe * a1.w;
                    facc[8] += pe * a2.x; facc[9] += pe * a2.y; facc[10] += pe * a2.z; facc[11] += pe * a2.w;
                    facc[12] += pe * a3.x; facc[13] += pe * a3.y; facc[14] += pe * a3.z; facc[15] += pe * a3.w;
                }
            }
            #pragma unroll
            for (int f = 0; f < 16; ++f) acc16[seg][j][f] = facc[f];
        }
        __syncthreads();
        {
            const int t = tid >> 4, f = tid & 15;
            float a = 0.f;
            #pragma unroll
            for (int k = 0; k < 16; ++k) a += acc16[t][k][f];
            float v = (1.f + eps) * h[t][f] + a;
            h[t][f] = fmaxf(v, 0.f);
        }
        __syncthreads();
    }

    for (int o = tid; o < 2048; o += 512) {
        const int t = o >> 6, d = o & 63;
        float s = 0.f;
        #pragma unroll
        for (int f = 0; f < 16; ++f) s += h[t][f] * W_e[f * 64 + d];
        hW[o] = s;
    }
}

__global__ __launch_bounds__(256) void tobf16_kernel(
    const float* __restrict__ x, unsigned short* __restrict__ y, int total8)
{
    const int i = blockIdx.x * 256 + threadIdx.x;
    if (i >= total8) return;
    const int base = i * 8;
    const float4 a = *reinterpret_cast<const float4*>(&x[base]);
    const float4 b = *reinterpret_cast<const float4*>(&x[base + 4]);
    us8 o;
    o[0] = f2b(a.x); o[1] = f2b(a.y); o[2] = f2b(a.z); o[3] = f2b(a.w);
    o[4] = f2b(b.x); o[5] = f2b(b.y); o[6] = f2b(b.z); o[7] = f2b(b.w);
    *reinterpret_cast<us8*>(&y[base]) = o;
}

__global__ __launch_bounds__(256) void bucket_count(
    const int* __restrict__ dst, int* __restrict__ bcnt, int E)
{
    __shared__ int lh[256];
    const int tid = threadIdx.x;
    lh[tid] = 0;
    __syncthreads();
    const int base = blockIdx.x * TILE;
    #pragma unroll
    for (int it = 0; it < 8; ++it) {
        const int i = base + (it * 256 + tid) * 4;
        if (i + 3 < E) {
            const int4 d = *reinterpret_cast<const int4*>(&dst[i]);
            atomicAdd(&lh[d.x >> 8], 1); atomicAdd(&lh[d.y >> 8], 1);
            atomicAdd(&lh[d.z >> 8], 1); atomicAdd(&lh[d.w >> 8], 1);
        } else {
            for (int k = i; k < E && k < i + 4; ++k) atomicAdd(&lh[dst[k] >> 8], 1);
        }
    }
    __syncthreads();
    if (lh[tid]) atomicAdd(&bcnt[tid], lh[tid]);
}

__global__ __launch_bounds__(256) void bucket_scan(
    const int* __restrict__ bcnt, int* __restrict__ bbase, int* __restrict__ bcur)
{
    __shared__ int ws[4];
    const int tid = threadIdx.x, lane = tid & 63, wv = tid >> 6;
    const int v = bcnt[tid];
    int x = v;
    #pragma unroll
    for (int s = 1; s < 64; s <<= 1) { const int t = __shfl_up(x, s, 64); if (lane >= s) x += t; }
    if (lane == 63) ws[wv] = x;
    __syncthreads();
    if (tid == 0) { int a = ws[0]; ws[0] = 0; for (int k = 1; k < 4; ++k) { const int b = ws[k]; ws[k] = a; a += b; } }
    __syncthreads();
    const int excl = ws[wv] + x - v;
    bbase[tid] = excl; bcur[tid] = excl;
    if (tid == 255) bbase[256] = excl + v;
}

__global__ __launch_bounds__(256) void bucket_scatter(
    const int* __restrict__ src, const int* __restrict__ dst, const int* __restrict__ et,
    int* __restrict__ bcur, unsigned* __restrict__ etmp, int E)
{
    __shared__ int lh[256], lofs[256], lcur[256], gbase[256];
    __shared__ int ws[4];
    __shared__ unsigned stage[TILE];
    __shared__ unsigned char sbk[TILE];
    const int tid = threadIdx.x, lane = tid & 63, wv = tid >> 6;
    lh[tid] = 0;
    __syncthreads();
    const int base = blockIdx.x * TILE;
    #pragma unroll
    for (int it = 0; it < 8; ++it) {
        const int i = base + (it * 256 + tid) * 4;
        if (i + 3 < E) {
            const int4 d = *reinterpret_cast<const int4*>(&dst[i]);
            atomicAdd(&lh[d.x >> 8], 1); atomicAdd(&lh[d.y >> 8], 1);
            atomicAdd(&lh[d.z >> 8], 1); atomicAdd(&lh[d.w >> 8], 1);
        } else {
            for (int k = i; k < E && k < i + 4; ++k) atomicAdd(&lh[dst[k] >> 8], 1);
        }
    }
    __syncthreads();
    {
        const int v = lh[tid];
        int x = v;
        #pragma unroll
        for (int s = 1; s < 64; s <<= 1) { const int t = __shfl_up(x, s, 64); if (lane >= s) x += t; }
        if (lane == 63) ws[wv] = x;
        __syncthreads();
        if (tid == 0) { int a = ws[0]; ws[0] = 0; for (int k = 1; k < 4; ++k) { const int b = ws[k]; ws[k] = a; a += b; } }
        __syncthreads();
        const int excl = ws[wv] + x - v;
        lofs[tid] = excl; lcur[tid] = excl;
        if (v) gbase[tid] = atomicAdd(&bcur[tid], v);
    }
    __syncthreads();
    #pragma unroll
    for (int it = 0; it < 8; ++it) {
        const int i = base + (it * 256 + tid) * 4;
        if (i + 3 < E) {
            const int4 d  = *reinterpret_cast<const int4*>(&dst[i]);
            const int4 s4 = *reinterpret_cast<const int4*>(&src[i]);
            const int4 t4 = *reinterpret_cast<const int4*>(&et[i]);
            int b, r;
            b = d.x >> 8; r = atomicAdd(&lcur[b], 1);
            stage[r] = (unsigned)s4.x | ((unsigned)(d.x & 255) << 16) | ((unsigned)t4.x << 24); sbk[r] = (unsigned char)b;
            b = d.y >> 8; r = atomicAdd(&lcur[b], 1);
            stage[r] = (unsigned)s4.y | ((unsigned)(d.y & 255) << 16) | ((unsigned)t4.y << 24); sbk[r] = (unsigned char)b;
            b = d.z >> 8; r = atomicAdd(&lcur[b], 1);
            stage[r] = (unsigned)s4.z | ((unsigned)(d.z & 255) << 16) | ((unsigned)t4.z << 24); sbk[r] = (unsigned char)b;
            b = d.w >> 8; r = atomicAdd(&lcur[b], 1);
            stage[r] = (unsigned)s4.w | ((unsigned)(d.w & 255) << 16) | ((unsigned)t4.w << 24); sbk[r] = (unsigned char)b;
        } else {
            for (int k = i; k < E && k < i + 4; ++k) {
                const int b = dst[k] >> 8;
                const int r = atomicAdd(&lcur[b], 1);
                stage[r] = (unsigned)src[k] | ((unsigned)(dst[k] & 255) << 16) | ((unsigned)et[k] << 24);
                sbk[r] = (unsigned char)b;
            }
        }
    }
    __syncthreads();
    const int tot = lofs[255] + lh[255];
    for (int i = tid; i < tot; i += 256) {
        const int b = sbk[i];
        etmp[gbase[b] + (i - lofs[b])] = stage[i];
    }
}

__global__ __launch_bounds__(256) void csr_kernel(
    const unsigned* __restrict__ etmp, const int* __restrict__ bbase,
    int* __restrict__ off, unsigned* __restrict__ ssrc, int N, int NB)
{
    __shared__ int lh[256], lofs[256], lcur[256];
    __shared__ int ws[4];
    const int tid = threadIdx.x, lane = tid & 63, wv = tid >> 6;
    const int b = blockIdx.x;
    const int s = bbase[b], e = bbase[b + 1];
    lh[tid] = 0;
    __syncthreads();
    for (int i = s + tid; i < e; i += 256)
        atomicAdd(&lh[(etmp[i] >> 16) & 255], 1);
    __syncthreads();
    {
        const int v = lh[tid];
        int x = v;
        #pragma unroll
        for (int ss = 1; ss < 64; ss <<= 1) { const int t = __shfl_up(x, ss, 64); if (lane >= ss) x += t; }
        if (lane == 63) ws[wv] = x;
        __syncthreads();
        if (tid == 0) { int a = ws[0]; ws[0] = 0; for (int k = 1; k < 4; ++k) { const int c = ws[k]; ws[k] = a; a += c; } }
        __syncthreads();
        const int excl = ws[wv] + x - v;
        lofs[tid] = excl; lcur[tid] = excl;
    }
    __syncthreads();
    const int n0 = b << 8;
    if (n0 + tid < N) off[n0 + tid] = s + lofs[tid];
    if (b == NB - 1 && tid == 0) off[N] = e;
    for (int i = s + tid; i < e; i += 256) {
        const unsigned pp = etmp[i];
        const int dl = (pp >> 16) & 255;
        const int r = atomicAdd(&lcur[dl], 1);
        ssrc[s + r] = pp;
    }
}

// aggF[n] = sum over incoming edges (bf16 gather[src] - hW[et]); fp32 accum + out
__global__ __launch_bounds__(256) void spmm_kernel(
    const unsigned short* __restrict__ fb, const float* __restrict__ hW,
    const int* __restrict__ off, const unsigned* __restrict__ ssrc,
    float* __restrict__ aggF, int N)
{
    __shared__ float hWl[2048];
    for (int i = threadIdx.x; i < 2048; i += 256) hWl[i] = hW[i];
    __syncthreads();
    const int lane = threadIdx.x & 63;
    const int n = blockIdx.x * 4 + (threadIdx.x >> 6);
    if (n >= N) return;
    const int half = lane >> 5, c = lane & 31;
    const int beg = off[n], end = off[n + 1];
    float a0 = 0.f, a1 = 0.f;
    int i = beg + half;
    for (; i + 6 < end; i += 8) {
        unsigned pp[4];
        #pragma unroll
        for (int jj = 0; jj < 4; ++jj) pp[jj] = ssrc[i + 2 * jj];
        #pragma unroll
        for (int jj = 0; jj < 4; ++jj) {
            const unsigned u = *reinterpret_cast<const unsigned*>(
                &fb[(size_t)(pp[jj] & 0xFFFFu) * 64 + 2 * c]);
            a0 += b2f((unsigned short)(u & 0xFFFFu));
            a1 += b2f((unsigned short)(u >> 16));
        }
        #pragma unroll
        for (int jj = 0; jj < 4; ++jj) {
            const float2 hw = *reinterpret_cast<const float2*>(
                &hWl[(pp[jj] >> 24) * 64 + 2 * c]);
            a0 -= hw.x; a1 -= hw.y;
        }
    }
    for (; i < end; i += 2) {
        const unsigned pp = ssrc[i];
        const unsigned u = *reinterpret_cast<const unsigned*>(
            &fb[(size_t)(pp & 0xFFFFu) * 64 + 2 * c]);
        const float2 hw = *reinterpret_cast<const float2*>(
            &hWl[(pp >> 24) * 64 + 2 * c]);
        a0 += b2f((unsigned short)(u & 0xFFFFu)) - hw.x;
        a1 += b2f((unsigned short)(u >> 16)) - hw.y;
    }
    a0 += __shfl_xor(a0, 32);
    a1 += __shfl_xor(a1, 32);
    if (half == 0)
        *reinterpret_cast<float2*>(&aggF[(size_t)n * 64 + 2 * c]) = make_float2(a0, a1);
}

// 4 threads/node x 16 outputs; X=[Xf|Af] fp32 in LDS (XOR-swizzled), W fp32 in LDS
__global__ __launch_bounds__(256) void gconv_kernel(
    const float* __restrict__ Xf, const float* __restrict__ Af,
    const float* __restrict__ W1, const float* __restrict__ W2,
    float* __restrict__ x1f, unsigned short* __restrict__ out16,
    float* __restrict__ outf,
    int N, int final_mode, const float* __restrict__ Wp, const float* __restrict__ bp)
{
    __shared__ float fa[64 * 128];   // 32 KB, float4-col XOR-swizzled
    __shared__ float Wl[128 * 64];   // 32 KB
    const int tid = threadIdx.x;
    const int nl = tid >> 2, sub = tid & 3;
    const int n0 = blockIdx.x * 64;
    const int n = n0 + nl;

    {
        const float4* w1v = reinterpret_cast<const float4*>(W1);
        const float4* w2v = reinterpret_cast<const float4*>(W2);
        float4* wlv = reinterpret_cast<float4*>(Wl);
        #pragma unroll
        for (int q = 0; q < 8; ++q) {
            const int idx = q * 256 + tid;
            wlv[idx] = (idx < 1024) ? w1v[idx] : w2v[idx - 1024];
        }
    }
    {
        float4* fav = reinterpret_cast<float4*>(fa);
        const float4* xv = reinterpret_cast<const float4*>(Xf);
        const float4* av = reinterpret_cast<const float4*>(Af);
        #pragma unroll
        for (int q = 0; q < 8; ++q) {
            const int cch = q * 256 + tid;           // 0..2047
            const int row = cch >> 5, p = cch & 31;
            const int rn = n0 + row;
            float4 v = make_float4(0.f, 0.f, 0.f, 0.f);
            if (rn < N)
                v = (p < 16) ? xv[(size_t)rn * 16 + p] : av[(size_t)rn * 16 + (p - 16)];
            fav[row * 32 + (p ^ ((row & 7) << 2))] = v;
        }
    }
    __syncthreads();

    float acc[16];
    #pragma unroll
    for (int d = 0; d < 16; ++d) acc[d] = 0.f;

    const int swz = (nl & 7) << 2;
    const float* farow = &fa[nl * 128];
    for (int k8 = 0; k8 < 16; ++k8) {
        const int c4 = (2 * k8) ^ swz;
        const float4 f0 = *reinterpret_cast<const float4*>(&farow[c4 * 4]);
        const float4 f1 = *reinterpret_cast<const float4*>(&farow[c4 * 4 + 4]);
        const float fv[8] = {f0.x, f0.y, f0.z, f0.w, f1.x, f1.y, f1.z, f1.w};
        #pragma unroll
        for (int j = 0; j < 8; ++j) {
            const float fval = fv[j];
            const float* wrow = &Wl[(k8 * 8 + j) * 64 + sub * 16];
            #pragma unroll
            for (int d4 = 0; d4 < 4; ++d4) {
                const float4 w = *reinterpret_cast<const float4*>(&wrow[d4 * 4]);
                acc[d4 * 4 + 0] += fval * w.x;
                acc[d4 * 4 + 1] += fval * w.y;
                acc[d4 * 4 + 2] += fval * w.z;
                acc[d4 * 4 + 3] += fval * w.w;
            }
        }
    }

    #pragma unroll
    for (int d = 0; d < 16; ++d) {
        const float e2 = __expf(2.f * acc[d]);
        acc[d] = 1.f - 2.f / (e2 + 1.f);
    }

    if (!final_mode) {
        if (n < N) {
            #pragma unroll
            for (int d4 = 0; d4 < 4; ++d4) {
                const float4 v = make_float4(acc[d4 * 4], acc[d4 * 4 + 1],
                                             acc[d4 * 4 + 2], acc[d4 * 4 + 3]);
                *reinterpret_cast<float4*>(&x1f[(size_t)n * 64 + sub * 16 + d4 * 4]) = v;
            }
            us8 o0, o1;
            #pragma unroll
            for (int d = 0; d < 8; ++d) { o0[d] = f2b(acc[d]); o1[d] = f2b(acc[8 + d]); }
            *reinterpret_cast<us8*>(&out16[(size_t)n * 64 + sub * 16]) = o0;
            *reinterpret_cast<us8*>(&out16[(size_t)n * 64 + sub * 16 + 8]) = o1;
        }
    } else {
        float o[16];
        #pragma unroll
        for (int c = 0; c < 16; ++c) o[c] = 0.f;
        #pragma unroll
        for (int dd = 0; dd < 16; ++dd) {
            const float t = acc[dd];
            const float* wp = &Wp[(sub * 16 + dd) * 16];
            #pragma unroll
            for (int c4 = 0; c4 < 4; ++c4) {
                const float4 w = *reinterpret_cast<const float4*>(&wp[c4 * 4]);
                o[c4 * 4 + 0] += t * w.x;
                o[c4 * 4 + 1] += t * w.y;
                o[c4 * 4 + 2] += t * w.z;
                o[c4 * 4 + 3] += t * w.w;
            }
        }
        #pragma unroll
        for (int c = 0; c < 16; ++c) {
            o[c] += __shfl_xor(o[c], 1);
            o[c] += __shfl_xor(o[c], 2);
        }
        if (sub == 0 && n < N) {
            #pragma unroll
            for (int c = 0; c < 16; ++c) o[c] += bp[c];
            #pragma unroll
            for (int c4 = 0; c4 < 4; ++c4) {
                const float4 v = make_float4(o[c4 * 4], o[c4 * 4 + 1],
                                             o[c4 * 4 + 2], o[c4 * 4 + 3]);
                *reinterpret_cast<float4*>(&outf[(size_t)n * 16 + c4 * 4]) = v;
            }
        }
    }
}

extern "C" void kernel_launch(void* const* d_in, const int* in_sizes, int n_in,
                              void* d_out, int out_size, void* d_ws, size_t ws_size,
                              hipStream_t stream)
{
    const float* cl_h   = (const float*)d_in[0];
    const float* cl_w   = (const float*)d_in[1];
    const int*   cl_src = (const int*)d_in[2];
    const int*   cl_dst = (const int*)d_in[3];
    const int*   g_src  = (const int*)d_in[4];
    const int*   g_dst  = (const int*)d_in[5];
    const int*   g_et   = (const int*)d_in[6];
    const float* feats  = (const float*)d_in[7];
    const float* W_e    = (const float*)d_in[8];
    const float* b1     = (const float*)d_in[9];
    const float* e1     = (const float*)d_in[10];
    const float* b2     = (const float*)d_in[11];
    const float* e2     = (const float*)d_in[12];
    const float* W1a    = (const float*)d_in[13];
    const float* W2a    = (const float*)d_in[14];
    const float* W1b    = (const float*)d_in[15];
    const float* W2b    = (const float*)d_in[16];
    const float* Wp     = (const float*)d_in[17];
    const float* bp     = (const float*)d_in[18];
    const int ECL = in_sizes[1];
    const int E   = in_sizes[4];
    const int N   = in_sizes[7] / 64;
    const int NB  = (N + 255) >> 8;

    char* w = (char*)d_ws;
    auto carve = [&](size_t bytes) {
        char* r = w;
        w += (bytes + 255) & ~(size_t)255;
        return r;
    };
    float*          hW    = (float*)carve(32 * 64 * sizeof(float));
    int*            off   = (int*)carve((size_t)(N + 1) * sizeof(int));
    int*            bcnt  = (int*)carve(256 * sizeof(int));
    int*            bbase = (int*)carve(257 * sizeof(int));
    int*            bcur  = (int*)carve(256 * sizeof(int));
    unsigned*       etmp  = (unsigned*)carve((size_t)E * sizeof(unsigned));
    unsigned*       ssrc  = (unsigned*)carve((size_t)E * sizeof(unsigned));
    unsigned short* fb16  = (unsigned short*)carve((size_t)N * 64 * sizeof(unsigned short));
    unsigned short* x16   = (unsigned short*)carve((size_t)N * 64 * sizeof(unsigned short));
    float*          aggF  = (float*)carve((size_t)N * 64 * sizeof(float));
    float*          x1f   = (float*)carve((size_t)N * 64 * sizeof(float));

    const int nblk = (E + TILE - 1) / TILE;
    const int total8 = N * 8;

    hipMemsetAsync(bcnt, 0, 256 * sizeof(int), stream);

    agnn_kernel<<<1, 512, 0, stream>>>(cl_h, cl_w, cl_src, cl_dst, W_e,
                                       b1, e1, b2, e2, hW, ECL);
    tobf16_kernel<<<(total8 + 255) / 256, 256, 0, stream>>>(feats, fb16, total8);
    bucket_count<<<nblk, 256, 0, stream>>>(g_dst, bcnt, E);
    bucket_scan<<<1, 256, 0, stream>>>(bcnt, bbase, bcur);
    bucket_scatter<<<nblk, 256, 0, stream>>>(g_src, g_dst, g_et, bcur, etmp, E);
    csr_kernel<<<NB, 256, 0, stream>>>(etmp, bbase, off, ssrc, N, NB);
    spmm_kernel<<<(N + 3) / 4, 256, 0, stream>>>(fb16, hW, off, ssrc, aggF, N);
    gconv_kernel<<<(N + 63) / 64, 256, 0, stream>>>(feats, aggF, W1a, W2a,
                                                    x1f, x16, nullptr, N, 0, Wp, bp);
    spmm_kernel<<<(N + 3) / 4, 256, 0, stream>>>(x16, hW, off, ssrc, aggF, N);
    gconv_kernel<<<(N + 63) / 64, 256, 0, stream>>>(x1f, aggF, W1b, W2b,
                                                    nullptr, nullptr, (float*)d_out, N, 1, Wp, bp);
}